// Round 6
// baseline (295.770 us; speedup 1.0000x reference)
//
#include <hip/hip_runtime.h>
#include <hip/hip_bf16.h>

// ---------------------------------------------------------------------------
// EncoderBlock round 15:
//  - r14 post-mortem: fp32-B in-GEMM conversion regressed (B latency exposed
//    each K-iter, MfmaUtil 15%). Reverted to r10-style full prep conversion.
//  - NEW: gemm128 K-loop rebuilt as triple-buffered counted-vmcnt pipeline
//    (T3/T4): 512 thr (8 waves, 2/SIMD), LDS 3x(16+16)KB = 96KB (1 blk/CU),
//    stage(it+2) issued after the iter-it barrier, s_waitcnt vmcnt(4) steady
//    state (vmcnt(0) only on final iter), ONE raw s_barrier per K-iter (no
//    full drain -> loads stay in flight across barriers), setprio(1) around
//    MFMA cluster (T5).
//    WAR safety: any wave past barrier it has consumed buf (it-1)%3 (its
//    ds_reads fed iter-(it-1) MFMAs); stage(it+2) targets that buf and is
//    issued after the barrier. RAW: vmcnt(4) retires stage(it) before the
//    barrier releases readers.
//  - attn / reduces / split-K=4 o-proj+fc2 / fused V-transpose unchanged.
// MFMA layouts (verified): A[m=lane&15][k=(lane>>4)*8+j],
//   B[k=(lane>>4)*8+j][n=lane&15], C/D row=(lane>>4)*4+reg, col=lane&15.
// ---------------------------------------------------------------------------

typedef __bf16 bf16;
typedef __attribute__((ext_vector_type(8))) __bf16 bf16x8;
typedef __attribute__((ext_vector_type(4))) __bf16 bf16x4;
typedef __attribute__((ext_vector_type(4))) float f32x4;

#define NTOK 2048
#define DM   1024
#define DFC  4096
#define QKVN 3072

__device__ inline void gl_lds16(const void* g, void* l) {
    __builtin_amdgcn_global_load_lds((const __attribute__((address_space(1))) void*)g,
                                     (__attribute__((address_space(3))) void*)l, 16, 0, 0);
}

// ---------------- LayerNorm row helper (torch: std ddof=1, /(std+eps)) -----
__device__ inline void ln_row(float4 v, const float* alpha, const float* beta,
                              bf16* outrow, int t) {
    float s  = v.x + v.y + v.z + v.w;
    float ss = v.x * v.x + v.y * v.y + v.z * v.z + v.w * v.w;
    __shared__ float red[8];
    int lane = t & 63, wv = t >> 6;
    #pragma unroll
    for (int o = 32; o > 0; o >>= 1) {
        s  += __shfl_down(s, o);
        ss += __shfl_down(ss, o);
    }
    if (lane == 0) { red[wv] = s; red[4 + wv] = ss; }
    __syncthreads();
    float S  = red[0] + red[1] + red[2] + red[3];
    float SS = red[4] + red[5] + red[6] + red[7];
    float mean = S * (1.0f / 1024.0f);
    float var  = (SS - S * mean) * (1.0f / 1023.0f);
    var = var < 0.f ? 0.f : var;
    float inv = 1.0f / (sqrtf(var) + 1e-6f);
    float4 a4 = reinterpret_cast<const float4*>(alpha)[t];
    float4 b4 = reinterpret_cast<const float4*>(beta)[t];
    bf16x4 o4;
    o4[0] = (bf16)(a4.x * (v.x - mean) * inv + b4.x);
    o4[1] = (bf16)(a4.y * (v.y - mean) * inv + b4.y);
    o4[2] = (bf16)(a4.z * (v.z - mean) * inv + b4.z);
    o4[3] = (bf16)(a4.w * (v.w - mean) * inv + b4.w);
    reinterpret_cast<bf16x4*>(outrow)[t] = o4;
}

// ---------------- prep: all weights fp32->bf16 AND ln1, one dispatch --------
__global__ __launch_bounds__(256) void prep_kernel(
    const float4* __restrict__ wq, const float4* __restrict__ wk,
    const float4* __restrict__ wv, const float4* __restrict__ wo,
    const float4* __restrict__ f1, const float4* __restrict__ f2,
    bf16x4* __restrict__ oqkv, bf16x4* __restrict__ oo,
    bf16x4* __restrict__ of1, bf16x4* __restrict__ of2,
    const float* __restrict__ x, const float* __restrict__ alpha1,
    const float* __restrict__ beta1, bf16* __restrict__ xn) {
    int blk = blockIdx.x;
    int t = threadIdx.x;
    if (blk < 12288) {
        int i = blk * 256 + t;
        const int Q = 262144;                        // 1024*1024/4
        float4 v;
        bf16x4* dst;
        if (i < 3 * Q) {
            v = (i < Q) ? wq[i] : (i < 2 * Q) ? wk[i - Q] : wv[i - 2 * Q];
            dst = oqkv + i;
        } else if (i < 4 * Q) {
            v = wo[i - 3 * Q];
            dst = oo + (i - 3 * Q);
        } else if (i < 8 * Q) {
            v = f1[i - 4 * Q];
            dst = of1 + (i - 4 * Q);
        } else {
            v = f2[i - 8 * Q];
            dst = of2 + (i - 8 * Q);
        }
        bf16x4 o;
        o[0] = (bf16)v.x; o[1] = (bf16)v.y; o[2] = (bf16)v.z; o[3] = (bf16)v.w;
        *dst = o;
    } else {
        int row = blk - 12288;
        float4 v = reinterpret_cast<const float4*>(x + (size_t)row * DM)[t];
        ln_row(v, alpha1, beta1, xn + (size_t)row * DM, t);
    }
}

// ---- o-proj split-K=4 reduce + residual -> x2, fused ln2 -> xn (block=row) -
__global__ __launch_bounds__(256) void reduce_ln_kernel(const float* __restrict__ p,
                                                        const float* __restrict__ resid,
                                                        const float* __restrict__ alpha,
                                                        const float* __restrict__ beta,
                                                        float* __restrict__ x2,
                                                        bf16* __restrict__ xn) {
    int row = blockIdx.x, t = threadIdx.x;
    size_t i4 = (size_t)row * 256 + t;
    const size_t SL = 524288;   // M*N/4 float4 per slice
    float4 a = reinterpret_cast<const float4*>(p)[i4];
    float4 b = reinterpret_cast<const float4*>(p)[i4 + SL];
    float4 c = reinterpret_cast<const float4*>(p)[i4 + 2 * SL];
    float4 d = reinterpret_cast<const float4*>(p)[i4 + 3 * SL];
    float4 r = reinterpret_cast<const float4*>(resid)[i4];
    float4 v;
    v.x = a.x + b.x + c.x + d.x + r.x;
    v.y = a.y + b.y + c.y + d.y + r.y;
    v.z = a.z + b.z + c.z + d.z + r.z;
    v.w = a.w + b.w + c.w + d.w + r.w;
    reinterpret_cast<float4*>(x2)[i4] = v;
    ln_row(v, alpha, beta, xn + (size_t)row * DM, t);
}

// ---- fc2 split-K=4 reduce + bias + residual -> d_out (fp32) ----------------
__global__ __launch_bounds__(256) void reduce_out_kernel(const float* __restrict__ p,
                                                         const float* __restrict__ bias,
                                                         const float* __restrict__ x2,
                                                         float* __restrict__ out) {
    size_t i4 = (size_t)blockIdx.x * 256 + threadIdx.x;
    const size_t SL = 524288;
    float4 a = reinterpret_cast<const float4*>(p)[i4];
    float4 b = reinterpret_cast<const float4*>(p)[i4 + SL];
    float4 c = reinterpret_cast<const float4*>(p)[i4 + 2 * SL];
    float4 d = reinterpret_cast<const float4*>(p)[i4 + 3 * SL];
    float4 r = reinterpret_cast<const float4*>(x2)[i4];
    float4 bi = reinterpret_cast<const float4*>(bias)[i4 & 255];
    float4 o;
    o.x = a.x + b.x + c.x + d.x + r.x + bi.x;
    o.y = a.y + b.y + c.y + d.y + r.y + bi.y;
    o.z = a.z + b.z + c.z + d.z + r.z + bi.z;
    o.w = a.w + b.w + c.w + d.w + r.w + bi.w;
    reinterpret_cast<float4*>(out)[i4] = o;
}

// ---------------- GEMM: 128x128 tile, BK=64, TRIPLE-buffer counted-vmcnt ----
// 512 threads = 8 waves (2M x 4N), per-wave out 64x32 (acc[4][2]).
// LDS: As[3]/Bs[3] 16KB each = 96KB. Stage = 4 gl_lds calls (2 A + 2 B).
// Pipeline: stage(it+2) issued AFTER iter-it barrier; vmcnt(4) steady
// (retires stage(it), leaves stage(it+1) in flight); vmcnt(0) last iter.
// LDS swizzle: chunk c of row m at pos c ^ (m&7) (write side: source chunk
// (tid&7)^(srow&7) stored linearly; read side: co = (q^(r&7))*8, ^32 for hi).
// EPI: 1 = relu(v+bias) bf16; 2 = QKV (V range n0>=2048 -> transposed vt);
//      4 = fp32 partial at z*M*N (split-K).
template <int EPI>
__global__ __launch_bounds__(512) void gemm128(const bf16* __restrict__ A,
                                               const bf16* __restrict__ Bt,
                                               void* __restrict__ outp,
                                               bf16* __restrict__ vt,
                                               const float* __restrict__ bias,
                                               int M, int N, int K, int kslice,
                                               int nbx, int nby) {
    __shared__ bf16 As[3][128 * 64];   // 48 KB
    __shared__ bf16 Bs[3][128 * 64];   // 48 KB
    int tid = threadIdx.x;
    int lane = tid & 63, wave = tid >> 6;
    int q = lane >> 4, r = lane & 15;
    int wm = wave >> 2, wn = wave & 3;

    // XCD-aware remap (nbx multiple of 8)
    int lid = blockIdx.y * nbx + blockIdx.x;
    int nxp = nbx >> 3;
    int xcd = lid & 7;
    int loc = lid >> 3;
    int bx = xcd * nxp + (loc % nxp);
    int by = loc / nxp;

    int m0 = by * 128, n0 = bx * 128;
    int kbeg = blockIdx.z * kslice;
    int nit = kslice / 64;
    f32x4 acc[4][2] = {};

    int srow = tid >> 3;               // 0..63
    int csrc = (tid & 7) ^ (srow & 7);
    const bf16* agp = A  + (size_t)(m0 + srow) * K + kbeg + csrc * 8;
    const bf16* bgp = Bt + (size_t)(n0 + srow) * K + kbeg + csrc * 8;

    int co0 = ((q ^ (r & 7)) * 8);
    int aoff = (wm * 64 + r) * 64;
    int boff = (wn * 32 + r) * 64;

    // one stage = 4 gl_lds (A rows 0-63, 64-127; B rows 0-63, 64-127)
    auto stage = [&](int it, int b) {
        int k0 = it * 64;
        gl_lds16(agp + k0,                      &As[b][tid * 8]);
        gl_lds16(agp + (size_t)64 * K + k0,     &As[b][4096 + tid * 8]);
        gl_lds16(bgp + k0,                      &Bs[b][tid * 8]);
        gl_lds16(bgp + (size_t)64 * K + k0,     &Bs[b][4096 + tid * 8]);
    };

    stage(0, 0);
    stage(1, 1);
    for (int it = 0; it < nit; ++it) {
        if (it + 1 < nit) asm volatile("s_waitcnt vmcnt(4)" ::: "memory");
        else              asm volatile("s_waitcnt vmcnt(0)" ::: "memory");
        __builtin_amdgcn_s_barrier();
        if (it + 2 < nit) stage(it + 2, (it + 2) % 3);

        const bf16* Ab = &As[it % 3][aoff];
        const bf16* Bb = &Bs[it % 3][boff];
        __builtin_amdgcn_s_setprio(1);
        #pragma unroll
        for (int half = 0; half < 2; ++half) {
            int co = co0 ^ (half * 32);
            bf16x8 af[4], bfv[2];
            #pragma unroll
            for (int t = 0; t < 4; ++t)
                af[t] = *reinterpret_cast<const bf16x8*>(Ab + t * 1024 + co);
            #pragma unroll
            for (int u = 0; u < 2; ++u)
                bfv[u] = *reinterpret_cast<const bf16x8*>(Bb + u * 1024 + co);
            #pragma unroll
            for (int t = 0; t < 4; ++t)
                #pragma unroll
                for (int u = 0; u < 2; ++u)
                    acc[t][u] = __builtin_amdgcn_mfma_f32_16x16x32_bf16(af[t], bfv[u], acc[t][u], 0, 0, 0);
        }
        __builtin_amdgcn_s_setprio(0);
    }

    // V-range blocks of the fused QKV gemm: write transposed into vt only.
    if (EPI == 2 && n0 >= 2048) {
        int bb = m0 >> 10;                       // tile never crosses b
        int sb = (m0 & 1023) + wm * 64 + q * 4;
        int vrow0 = bb * 1024 + (n0 - 2048) + wn * 32;
        #pragma unroll
        for (int t = 0; t < 4; ++t) {
            #pragma unroll
            for (int u = 0; u < 2; ++u) {
                bf16x4 pk;
                #pragma unroll
                for (int i = 0; i < 4; ++i) pk[i] = (bf16)acc[t][u][i];
                *reinterpret_cast<bf16x4*>(vt + (size_t)(vrow0 + u * 16 + r) * 1024 + sb + t * 16) = pk;
            }
        }
        return;
    }

    size_t zoff = (size_t)blockIdx.z * M * N;
    #pragma unroll
    for (int t = 0; t < 4; ++t) {
        #pragma unroll
        for (int u = 0; u < 2; ++u) {
            #pragma unroll
            for (int i = 0; i < 4; ++i) {
                int mm = m0 + wm * 64 + t * 16 + q * 4 + i;
                int nn = n0 + wn * 32 + u * 16 + r;
                size_t idx = (size_t)mm * N + nn;
                float v = acc[t][u][i];
                if (EPI == 1) {
                    v += bias[nn];
                    ((bf16*)outp)[idx] = (bf16)(v > 0.f ? v : 0.f);
                } else if (EPI == 2) {
                    ((bf16*)outp)[idx] = (bf16)v;
                } else {
                    ((float*)outp)[zoff + idx] = v;
                }
            }
        }
    }
}

// ---------------- flash attention: 64 q-rows/block, LDS-staged K/V ----------
__global__ __launch_bounds__(256) void attn_kernel(const bf16* __restrict__ qkv,
                                                   const bf16* __restrict__ Vt,
                                                   const int* __restrict__ mask,
                                                   bf16* __restrict__ out) {
    __shared__ bf16 Ks[2][4096];     // 16 KB
    __shared__ bf16 Vs[2][4096];     // 16 KB
    __shared__ bf16 pbuf[4][1024];   // 8 KB
    __shared__ float msk[1024];      // 4 KB
    int tid = threadIdx.x;
    int lane = tid & 63, w = tid >> 6;
    int q = lane >> 4, r = lane & 15;

    int id = blockIdx.x;
    int xcd = id & 7, j = id >> 3;       // j in [0,64)
    int bh = xcd * 4 + (j >> 4);         // [0,32)
    int qb = j & 15;
    int b = bh >> 4, h = bh & 15;

    {
        int4 mi = reinterpret_cast<const int4*>(mask + b * 1024)[tid];
        msk[tid * 4 + 0] = mi.x ? 0.f : -1e9f;
        msk[tid * 4 + 1] = mi.y ? 0.f : -1e9f;
        msk[tid * 4 + 2] = mi.z ? 0.f : -1e9f;
        msk[tid * 4 + 3] = mi.w ? 0.f : -1e9f;
    }

    const bf16* qrow = qkv + (size_t)(b * 1024 + qb * 64 + w * 16 + r) * QKVN + h * 64 + q * 8;
    bf16x8 qf0 = *reinterpret_cast<const bf16x8*>(qrow);
    bf16x8 qf1 = *reinterpret_cast<const bf16x8*>(qrow + 32);

    int csw = (tid & 7) ^ ((tid >> 3) & 7);
    const bf16* kg0 = qkv + (size_t)(b * 1024 + (tid >> 3)) * QKVN + 1024 + h * 64 + csw * 8;
    const bf16* kg1 = kg0 + (size_t)32 * QKVN;
    const bf16* vg0 = Vt + (size_t)((b * 16 + h) * 64 + (tid >> 3)) * 1024 + csw * 8;
    const bf16* vg1 = vg0 + 32 * 1024;
    bf16* kld = &Ks[0][tid * 8];
    bf16* vld = &Vs[0][tid * 8];

    int co0 = (q ^ (r & 7)) * 8;
    bf16* pw = pbuf[w];
    bf16x8 ones;
    #pragma unroll
    for (int jj = 0; jj < 8; ++jj) ones[jj] = (bf16)1.0f;

    float m[4] = {-1e30f, -1e30f, -1e30f, -1e30f};
    f32x4 osum = {};
    f32x4 o[4] = {};

    gl_lds16(kg0, kld);
    gl_lds16(kg1, kld + 2048);
    gl_lds16(vg0, vld);
    gl_lds16(vg1, vld + 2048);

    for (int t = 0; t < 16; ++t) {
        __syncthreads();
        if (t < 15) {
            int ktn = (t + 1) * 64;
            int bo = ((t + 1) & 1) * 4096;
            gl_lds16(kg0 + (size_t)ktn * QKVN, kld + bo);
            gl_lds16(kg1 + (size_t)ktn * QKVN, kld + bo + 2048);
            gl_lds16(vg0 + ktn, vld + bo);
            gl_lds16(vg1 + ktn, vld + bo + 2048);
        }
        const bf16* Kb = Ks[t & 1];
        const bf16* Vb = Vs[t & 1];
        int kt = t * 64;

        f32x4 s[4];
        #pragma unroll
        for (int ks = 0; ks < 4; ++ks) {
            bf16x8 kf0 = *reinterpret_cast<const bf16x8*>(&Kb[(ks * 16 + r) * 64 + co0]);
            bf16x8 kf1 = *reinterpret_cast<const bf16x8*>(&Kb[(ks * 16 + r) * 64 + (co0 ^ 32)]);
            f32x4 a = {};
            a = __builtin_amdgcn_mfma_f32_16x16x32_bf16(qf0, kf0, a, 0, 0, 0);
            a = __builtin_amdgcn_mfma_f32_16x16x32_bf16(qf1, kf1, a, 0, 0, 0);
            float mb = msk[kt + ks * 16 + r];
            #pragma unroll
            for (int i = 0; i < 4; ++i) s[ks][i] = fmaf(a[i], 0.125f, mb);
        }
        float alpha[4];
        #pragma unroll
        for (int i = 0; i < 4; ++i) {
            float t2 = fmaxf(fmaxf(s[0][i], s[1][i]), fmaxf(s[2][i], s[3][i]));
            t2 = fmaxf(t2, __shfl_xor(t2, 1));
            t2 = fmaxf(t2, __shfl_xor(t2, 2));
            t2 = fmaxf(t2, __shfl_xor(t2, 4));
            t2 = fmaxf(t2, __shfl_xor(t2, 8));
            float mn = fmaxf(m[i], t2);
            alpha[i] = __expf(m[i] - mn);
            m[i] = mn;
        }
        #pragma unroll
        for (int i = 0; i < 4; ++i) {
            s[0][i] = __expf(s[0][i] - m[i]);
            s[1][i] = __expf(s[1][i] - m[i]);
            s[2][i] = __expf(s[2][i] - m[i]);
            s[3][i] = __expf(s[3][i] - m[i]);
        }
        #pragma unroll
        for (int i = 0; i < 4; ++i) {
            osum[i] *= alpha[i];
            o[0][i] *= alpha[i]; o[1][i] *= alpha[i];
            o[2][i] *= alpha[i]; o[3][i] *= alpha[i];
        }
        #pragma unroll
        for (int ks = 0; ks < 4; ++ks) {
            int kc = ks * 2 + (r >> 3);
            #pragma unroll
            for (int i = 0; i < 4; ++i) {
                int mr = q * 4 + i;
                pw[mr * 64 + ((kc ^ (mr & 7)) * 8) + (r & 7)] = (bf16)s[ks][i];
            }
        }
        #pragma unroll
        for (int ks2 = 0; ks2 < 2; ++ks2) {
            int vpo = (((ks2 * 4 + q) ^ (r & 7)) * 8);
            bf16x8 pf = *reinterpret_cast<const bf16x8*>(&pw[r * 64 + vpo]);
            #pragma unroll
            for (int nt = 0; nt < 4; ++nt) {
                bf16x8 vf = *reinterpret_cast<const bf16x8*>(&Vb[(nt * 16 + r) * 64 + vpo]);
                o[nt] = __builtin_amdgcn_mfma_f32_16x16x32_bf16(pf, vf, o[nt], 0, 0, 0);
            }
            osum = __builtin_amdgcn_mfma_f32_16x16x32_bf16(pf, ones, osum, 0, 0, 0);
        }
    }

    float inv[4];
    #pragma unroll
    for (int i = 0; i < 4; ++i) inv[i] = 1.0f / osum[i];
    #pragma unroll
    for (int nt = 0; nt < 4; ++nt)
        #pragma unroll
        for (int i = 0; i < 4; ++i)
            out[(size_t)(b * 1024 + qb * 64 + w * 16 + q * 4 + i) * DM + h * 64 + nt * 16 + r] =
                (bf16)(o[nt][i] * inv[i]);
}

// ---------------------------------------------------------------------------
extern "C" void kernel_launch(void* const* d_in, const int* in_sizes, int n_in,
                              void* d_out, int out_size, void* d_ws, size_t ws_size,
                              hipStream_t stream) {
    const float* x      = (const float*)d_in[0];
    const int*   mask   = (const int*)  d_in[1];
    const float* w_q    = (const float*)d_in[2];
    const float* w_k    = (const float*)d_in[3];
    const float* w_v    = (const float*)d_in[4];
    const float* w_o    = (const float*)d_in[5];
    const float* alpha1 = (const float*)d_in[6];
    const float* beta1  = (const float*)d_in[7];
    const float* alpha2 = (const float*)d_in[8];
    const float* beta2  = (const float*)d_in[9];
    const float* fc1_w  = (const float*)d_in[10];
    const float* fc1_b  = (const float*)d_in[11];
    const float* fc2_w  = (const float*)d_in[12];
    const float* fc2_b  = (const float*)d_in[13];
    float* out = (float*)d_out;

    char* ws = (char*)d_ws;
    const size_t MB = 1024 * 1024;
    bf16*  wqkv_b = (bf16*)(ws +  0 * MB);   // 6 MB
    bf16*  wo_b   = (bf16*)(ws +  6 * MB);   // 2 MB
    bf16*  f1w_b  = (bf16*)(ws +  8 * MB);   // 8 MB
    bf16*  f2w_b  = (bf16*)(ws + 16 * MB);   // 8 MB
    bf16*  xn     = (bf16*)(ws + 24 * MB);   // 4 MB
    bf16*  qkvb   = (bf16*)(ws + 28 * MB);   // 12 MB (Q,K; dead after attn)
    bf16*  vtb    = (bf16*)(ws + 40 * MB);   // 4 MB  (dead after attn)
    bf16*  attnb  = (bf16*)(ws + 44 * MB);   // 4 MB  (dead after o-proj)
    float* x2     = (float*)(ws + 48 * MB);  // 8 MB
    float* po     = (float*)(ws + 56 * MB);  // 32 MB o-proj partials (4 slices)
    bf16*  hb     = (bf16*)(ws + 28 * MB);   // 16 MB fc1 out (over qkvb/vtb)
    float* pf2    = (float*)(ws + 56 * MB);  // 32 MB fc2 partials (over po)

    // 1) weights -> bf16 + ln1, one dispatch
    prep_kernel<<<14336, 256, 0, stream>>>(
        (const float4*)w_q, (const float4*)w_k, (const float4*)w_v, (const float4*)w_o,
        (const float4*)fc1_w, (const float4*)fc2_w,
        (bf16x4*)wqkv_b, (bf16x4*)wo_b, (bf16x4*)f1w_b, (bf16x4*)f2w_b,
        x, alpha1, beta1, xn);

    // 2) fused QKV projection (grid 24x16); V-range blocks write vtb
    gemm128<2><<<dim3(24, 16, 1), 512, 0, stream>>>(
        xn, wqkv_b, qkvb, vtb, nullptr, NTOK, QKVN, DM, DM, 24, 16);

    // 3) flash attention (512 blocks, XCD-swizzled)
    attn_kernel<<<512, 256, 0, stream>>>(qkvb, vtb, mask, attnb);

    // 4) o-proj split-K=4 partials (grid 8x16x4)
    gemm128<4><<<dim3(8, 16, 4), 512, 0, stream>>>(
        attnb, wo_b, po, nullptr, nullptr, NTOK, DM, DM, DM / 4, 8, 16);

    // 5) reduce + residual -> x2, fused ln2 -> xn
    reduce_ln_kernel<<<NTOK, 256, 0, stream>>>(po, x, alpha2, beta2, x2, xn);

    // 6) fc1 + bias + relu (grid 32x16)
    gemm128<1><<<dim3(32, 16, 1), 512, 0, stream>>>(
        xn, f1w_b, hb, nullptr, fc1_b, NTOK, DFC, DM, DM, 32, 16);

    // 7) fc2 split-K=4 partials (grid 8x16x4)
    gemm128<4><<<dim3(8, 16, 4), 512, 0, stream>>>(
        hb, f2w_b, pf2, nullptr, nullptr, NTOK, DM, DFC, DFC / 4, 8, 16);

    // 8) bias + residual -> out
    reduce_out_kernel<<<2048, 256, 0, stream>>>(pf2, fc2_b, x2, out);
}

// Round 7
// 258.809 us; speedup vs baseline: 1.1428x; 1.1428x over previous
//
#include <hip/hip_runtime.h>
#include <hip/hip_bf16.h>

// ---------------------------------------------------------------------------
// EncoderBlock round 16:
//  - Diagnosis from r13/r14/r15 failures: gemms are STAGING-BW/L2-locality
//    bound (64 FLOP/B at 128x128, FETCH ~3x compulsory) -> schedule rebuilds
//    are null; tile economics are the lever.
//  - Revert all schedules to the proven r12 2-barrier structure.
//  - NEW gemm_wide: 128x256 tile, BK=64, 512 thr (8 waves 2Mx4N, acc[4][4]
//    per wave = same MFMA density as r12), LDS 96KB dbuf, 87 FLOP/B staged.
//    Used for fc1 (grid 16x16, B-slice 1MB/XCD L2-resident) and fc2
//    (grid 4x16 x split-K=4, kslice=1024).
//  - QKV/o-proj: r12 gemm128 (256 thr). prep: r10 full conversion + ln1.
// MFMA layouts (verified): A[m=lane&15][k=(lane>>4)*8+j],
//   B[k=(lane>>4)*8+j][n=lane&15], C/D row=(lane>>4)*4+reg, col=lane&15.
// ---------------------------------------------------------------------------

typedef __bf16 bf16;
typedef __attribute__((ext_vector_type(8))) __bf16 bf16x8;
typedef __attribute__((ext_vector_type(4))) __bf16 bf16x4;
typedef __attribute__((ext_vector_type(4))) float f32x4;

#define NTOK 2048
#define DM   1024
#define DFC  4096
#define QKVN 3072

__device__ inline void gl_lds16(const void* g, void* l) {
    __builtin_amdgcn_global_load_lds((const __attribute__((address_space(1))) void*)g,
                                     (__attribute__((address_space(3))) void*)l, 16, 0, 0);
}

// ---------------- LayerNorm row helper (torch: std ddof=1, /(std+eps)) -----
__device__ inline void ln_row(float4 v, const float* alpha, const float* beta,
                              bf16* outrow, int t) {
    float s  = v.x + v.y + v.z + v.w;
    float ss = v.x * v.x + v.y * v.y + v.z * v.z + v.w * v.w;
    __shared__ float red[8];
    int lane = t & 63, wv = t >> 6;
    #pragma unroll
    for (int o = 32; o > 0; o >>= 1) {
        s  += __shfl_down(s, o);
        ss += __shfl_down(ss, o);
    }
    if (lane == 0) { red[wv] = s; red[4 + wv] = ss; }
    __syncthreads();
    float S  = red[0] + red[1] + red[2] + red[3];
    float SS = red[4] + red[5] + red[6] + red[7];
    float mean = S * (1.0f / 1024.0f);
    float var  = (SS - S * mean) * (1.0f / 1023.0f);
    var = var < 0.f ? 0.f : var;
    float inv = 1.0f / (sqrtf(var) + 1e-6f);
    float4 a4 = reinterpret_cast<const float4*>(alpha)[t];
    float4 b4 = reinterpret_cast<const float4*>(beta)[t];
    bf16x4 o4;
    o4[0] = (bf16)(a4.x * (v.x - mean) * inv + b4.x);
    o4[1] = (bf16)(a4.y * (v.y - mean) * inv + b4.y);
    o4[2] = (bf16)(a4.z * (v.z - mean) * inv + b4.z);
    o4[3] = (bf16)(a4.w * (v.w - mean) * inv + b4.w);
    reinterpret_cast<bf16x4*>(outrow)[t] = o4;
}

// ---------------- prep: all weights fp32->bf16 AND ln1, one dispatch --------
__global__ __launch_bounds__(256) void prep_kernel(
    const float4* __restrict__ wq, const float4* __restrict__ wk,
    const float4* __restrict__ wv, const float4* __restrict__ wo,
    const float4* __restrict__ f1, const float4* __restrict__ f2,
    bf16x4* __restrict__ oqkv, bf16x4* __restrict__ oo,
    bf16x4* __restrict__ of1, bf16x4* __restrict__ of2,
    const float* __restrict__ x, const float* __restrict__ alpha1,
    const float* __restrict__ beta1, bf16* __restrict__ xn) {
    int blk = blockIdx.x;
    int t = threadIdx.x;
    if (blk < 12288) {
        int i = blk * 256 + t;
        const int Q = 262144;                        // 1024*1024/4
        float4 v;
        bf16x4* dst;
        if (i < 3 * Q) {
            v = (i < Q) ? wq[i] : (i < 2 * Q) ? wk[i - Q] : wv[i - 2 * Q];
            dst = oqkv + i;
        } else if (i < 4 * Q) {
            v = wo[i - 3 * Q];
            dst = oo + (i - 3 * Q);
        } else if (i < 8 * Q) {
            v = f1[i - 4 * Q];
            dst = of1 + (i - 4 * Q);
        } else {
            v = f2[i - 8 * Q];
            dst = of2 + (i - 8 * Q);
        }
        bf16x4 o;
        o[0] = (bf16)v.x; o[1] = (bf16)v.y; o[2] = (bf16)v.z; o[3] = (bf16)v.w;
        *dst = o;
    } else {
        int row = blk - 12288;
        float4 v = reinterpret_cast<const float4*>(x + (size_t)row * DM)[t];
        ln_row(v, alpha1, beta1, xn + (size_t)row * DM, t);
    }
}

// ---- o-proj split-K=4 reduce + residual -> x2, fused ln2 -> xn (block=row) -
__global__ __launch_bounds__(256) void reduce_ln_kernel(const float* __restrict__ p,
                                                        const float* __restrict__ resid,
                                                        const float* __restrict__ alpha,
                                                        const float* __restrict__ beta,
                                                        float* __restrict__ x2,
                                                        bf16* __restrict__ xn) {
    int row = blockIdx.x, t = threadIdx.x;
    size_t i4 = (size_t)row * 256 + t;
    const size_t SL = 524288;   // M*N/4 float4 per slice
    float4 a = reinterpret_cast<const float4*>(p)[i4];
    float4 b = reinterpret_cast<const float4*>(p)[i4 + SL];
    float4 c = reinterpret_cast<const float4*>(p)[i4 + 2 * SL];
    float4 d = reinterpret_cast<const float4*>(p)[i4 + 3 * SL];
    float4 r = reinterpret_cast<const float4*>(resid)[i4];
    float4 v;
    v.x = a.x + b.x + c.x + d.x + r.x;
    v.y = a.y + b.y + c.y + d.y + r.y;
    v.z = a.z + b.z + c.z + d.z + r.z;
    v.w = a.w + b.w + c.w + d.w + r.w;
    reinterpret_cast<float4*>(x2)[i4] = v;
    ln_row(v, alpha, beta, xn + (size_t)row * DM, t);
}

// ---- fc2 split-K=4 reduce + bias + residual -> d_out (fp32) ----------------
__global__ __launch_bounds__(256) void reduce_out_kernel(const float* __restrict__ p,
                                                         const float* __restrict__ bias,
                                                         const float* __restrict__ x2,
                                                         float* __restrict__ out) {
    size_t i4 = (size_t)blockIdx.x * 256 + threadIdx.x;
    const size_t SL = 524288;
    float4 a = reinterpret_cast<const float4*>(p)[i4];
    float4 b = reinterpret_cast<const float4*>(p)[i4 + SL];
    float4 c = reinterpret_cast<const float4*>(p)[i4 + 2 * SL];
    float4 d = reinterpret_cast<const float4*>(p)[i4 + 3 * SL];
    float4 r = reinterpret_cast<const float4*>(x2)[i4];
    float4 bi = reinterpret_cast<const float4*>(bias)[i4 & 255];
    float4 o;
    o.x = a.x + b.x + c.x + d.x + r.x + bi.x;
    o.y = a.y + b.y + c.y + d.y + r.y + bi.y;
    o.z = a.z + b.z + c.z + d.z + r.z + bi.z;
    o.w = a.w + b.w + c.w + d.w + r.w + bi.w;
    reinterpret_cast<float4*>(out)[i4] = o;
}

// ---------------- GEMM: 128x128 tile, BK=64, dbuf, swizzled LDS (r12) -------
// EPI: 2 = QKV (V range n0>=2048 -> transposed store into vt); 4 = fp32
//      partial at z*M*N (split-K).
template <int EPI>
__global__ __launch_bounds__(256) void gemm128(const bf16* __restrict__ A,
                                               const bf16* __restrict__ Bt,
                                               void* __restrict__ outp,
                                               bf16* __restrict__ vt,
                                               int M, int N, int K, int kslice,
                                               int nbx, int nby) {
    __shared__ bf16 As[2][128 * 64];   // 32 KB
    __shared__ bf16 Bs[2][128 * 64];   // 32 KB
    int tid = threadIdx.x;
    int lane = tid & 63, wave = tid >> 6;
    int q = lane >> 4, r = lane & 15;
    int wm = wave >> 1, wn = wave & 1;

    int lid = blockIdx.y * nbx + blockIdx.x;
    int nxp = nbx >> 3;
    int xcd = lid & 7;
    int loc = lid >> 3;
    int bx = xcd * nxp + (loc % nxp);
    int by = loc / nxp;

    int m0 = by * 128, n0 = bx * 128;
    int kbeg = blockIdx.z * kslice;
    int nit = kslice / 64;
    f32x4 acc[4][4] = {};

    int srow = tid >> 3;
    int csrc = (tid & 7) ^ (srow & 7);
    const bf16* agp = A  + (size_t)(m0 + srow) * K + kbeg + csrc * 8;
    const bf16* bgp = Bt + (size_t)(n0 + srow) * K + kbeg + csrc * 8;

    int co0 = ((q ^ (r & 7)) * 8);
    int co1 = co0 ^ 32;
    int aoff = (wm * 64 + r) * 64;
    int boff = (wn * 64 + r) * 64;

    auto stage = [&](int it, int b) {
        int k0 = it * 64;
        #pragma unroll
        for (int j = 0; j < 4; ++j) {
            gl_lds16(agp + (size_t)j * 32 * K + k0, &As[b][tid * 8 + j * 2048]);
            gl_lds16(bgp + (size_t)j * 32 * K + k0, &Bs[b][tid * 8 + j * 2048]);
        }
    };

    stage(0, 0);
    for (int it = 0; it < nit; ++it) {
        __syncthreads();                       // drains stage(it)
        if (it + 1 < nit) stage(it + 1, (it + 1) & 1);
        const bf16* Ab = &As[it & 1][aoff];
        const bf16* Bb = &Bs[it & 1][boff];
        #pragma unroll
        for (int half = 0; half < 2; ++half) {
            int co = half ? co1 : co0;
            bf16x8 af[4], bfv[4];
            #pragma unroll
            for (int t = 0; t < 4; ++t)
                af[t] = *reinterpret_cast<const bf16x8*>(Ab + t * 1024 + co);
            #pragma unroll
            for (int u = 0; u < 4; ++u)
                bfv[u] = *reinterpret_cast<const bf16x8*>(Bb + u * 1024 + co);
            #pragma unroll
            for (int t = 0; t < 4; ++t)
                #pragma unroll
                for (int u = 0; u < 4; ++u)
                    acc[t][u] = __builtin_amdgcn_mfma_f32_16x16x32_bf16(af[t], bfv[u], acc[t][u], 0, 0, 0);
        }
    }

    if (EPI == 2 && n0 >= 2048) {
        int bb = m0 >> 10;
        int sb = (m0 & 1023) + wm * 64 + q * 4;
        int vrow0 = bb * 1024 + (n0 - 2048) + wn * 64;
        #pragma unroll
        for (int t = 0; t < 4; ++t) {
            #pragma unroll
            for (int u = 0; u < 4; ++u) {
                bf16x4 pk;
                #pragma unroll
                for (int i = 0; i < 4; ++i) pk[i] = (bf16)acc[t][u][i];
                *reinterpret_cast<bf16x4*>(vt + (size_t)(vrow0 + u * 16 + r) * 1024 + sb + t * 16) = pk;
            }
        }
        return;
    }

    size_t zoff = (size_t)blockIdx.z * M * N;
    #pragma unroll
    for (int t = 0; t < 4; ++t) {
        #pragma unroll
        for (int u = 0; u < 4; ++u) {
            #pragma unroll
            for (int i = 0; i < 4; ++i) {
                int mm = m0 + wm * 64 + t * 16 + q * 4 + i;
                int nn = n0 + wn * 64 + u * 16 + r;
                size_t idx = (size_t)mm * N + nn;
                float v = acc[t][u][i];
                if (EPI == 2) {
                    ((bf16*)outp)[idx] = (bf16)v;
                } else {
                    ((float*)outp)[zoff + idx] = v;
                }
            }
        }
    }
}

// ---------------- GEMM: 128x256 tile, BK=64, 512 thr, dbuf, swizzled LDS ----
// 8 waves (2M x 4N), per-wave out 64x64 = acc[4][4] (same MFMA density as
// gemm128). Staged 48KB/step for 4.2 MFLOP = 87 FLOP/B (1.37x gemm128).
// Same 2-barrier schedule, same LDS swizzle (row*64 + (c^(row&7))*8).
// EPI: 1 = relu(v+bias) bf16; 4 = fp32 partial at z*M*N.
template <int EPI>
__global__ __launch_bounds__(512) void gemm_wide(const bf16* __restrict__ A,
                                                 const bf16* __restrict__ Bt,
                                                 void* __restrict__ outp,
                                                 const float* __restrict__ bias,
                                                 int M, int N, int K, int kslice,
                                                 int nbx, int nby) {
    __shared__ bf16 As[2][128 * 64];   // 32 KB
    __shared__ bf16 Bs[2][256 * 64];   // 64 KB
    int tid = threadIdx.x;
    int lane = tid & 63, wave = tid >> 6;
    int q = lane >> 4, r = lane & 15;
    int wm = wave >> 2, wn = wave & 3;

    int bx, by;
    if (nbx >= 8) {                    // XCD-aware remap (nbx multiple of 8)
        int lid = blockIdx.y * nbx + blockIdx.x;
        int nxp = nbx >> 3;
        int xcd = lid & 7;
        int loc = lid >> 3;
        bx = xcd * nxp + (loc % nxp);
        by = loc / nxp;
    } else {
        bx = blockIdx.x; by = blockIdx.y;
    }

    int m0 = by * 128, n0 = bx * 256;
    int kbeg = blockIdx.z * kslice;
    int nit = kslice / 64;
    f32x4 acc[4][4] = {};

    int srow = tid >> 3;               // 0..63 (8 threads x 8 bf16 = 64 cols)
    int csrc = (tid & 7) ^ (srow & 7);
    const bf16* agp = A  + (size_t)(m0 + srow) * K + kbeg + csrc * 8;
    const bf16* bgp = Bt + (size_t)(n0 + srow) * K + kbeg + csrc * 8;

    int co0 = ((q ^ (r & 7)) * 8);
    int aoff = (wm * 64 + r) * 64;     // A rows: wm*64 + t*16 + r
    int boff = (wn * 64 + r) * 64;     // B rows: wn*64 + u*16 + r

    // stage: A 2 chunks of 64 rows, B 4 chunks of 64 rows (48 KB total)
    auto stage = [&](int it, int b) {
        int k0 = it * 64;
        gl_lds16(agp + k0,                  &As[b][tid * 8]);
        gl_lds16(agp + (size_t)64 * K + k0, &As[b][4096 + tid * 8]);
        #pragma unroll
        for (int c = 0; c < 4; ++c)
            gl_lds16(bgp + (size_t)(c * 64) * K + k0, &Bs[b][c * 4096 + tid * 8]);
    };

    stage(0, 0);
    for (int it = 0; it < nit; ++it) {
        __syncthreads();                       // drains stage(it)
        if (it + 1 < nit) stage(it + 1, (it + 1) & 1);
        const bf16* Ab = &As[it & 1][aoff];
        const bf16* Bb = &Bs[it & 1][boff];
        #pragma unroll
        for (int half = 0; half < 2; ++half) {
            int co = co0 ^ (half * 32);
            bf16x8 af[4], bfv[4];
            #pragma unroll
            for (int t = 0; t < 4; ++t)
                af[t] = *reinterpret_cast<const bf16x8*>(Ab + t * 1024 + co);
            #pragma unroll
            for (int u = 0; u < 4; ++u)
                bfv[u] = *reinterpret_cast<const bf16x8*>(Bb + u * 1024 + co);
            #pragma unroll
            for (int t = 0; t < 4; ++t)
                #pragma unroll
                for (int u = 0; u < 4; ++u)
                    acc[t][u] = __builtin_amdgcn_mfma_f32_16x16x32_bf16(af[t], bfv[u], acc[t][u], 0, 0, 0);
        }
    }

    size_t zoff = (size_t)blockIdx.z * M * N;
    #pragma unroll
    for (int t = 0; t < 4; ++t) {
        #pragma unroll
        for (int u = 0; u < 4; ++u) {
            #pragma unroll
            for (int i = 0; i < 4; ++i) {
                int mm = m0 + wm * 64 + t * 16 + q * 4 + i;
                int nn = n0 + wn * 64 + u * 16 + r;
                size_t idx = (size_t)mm * N + nn;
                float v = acc[t][u][i];
                if (EPI == 1) {
                    v += bias[nn];
                    ((bf16*)outp)[idx] = (bf16)(v > 0.f ? v : 0.f);
                } else {
                    ((float*)outp)[zoff + idx] = v;
                }
            }
        }
    }
}

// ---------------- flash attention: 64 q-rows/block, LDS-staged K/V ----------
__global__ __launch_bounds__(256) void attn_kernel(const bf16* __restrict__ qkv,
                                                   const bf16* __restrict__ Vt,
                                                   const int* __restrict__ mask,
                                                   bf16* __restrict__ out) {
    __shared__ bf16 Ks[2][4096];     // 16 KB
    __shared__ bf16 Vs[2][4096];     // 16 KB
    __shared__ bf16 pbuf[4][1024];   // 8 KB
    __shared__ float msk[1024];      // 4 KB
    int tid = threadIdx.x;
    int lane = tid & 63, w = tid >> 6;
    int q = lane >> 4, r = lane & 15;

    int id = blockIdx.x;
    int xcd = id & 7, j = id >> 3;       // j in [0,64)
    int bh = xcd * 4 + (j >> 4);         // [0,32)
    int qb = j & 15;
    int b = bh >> 4, h = bh & 15;

    {
        int4 mi = reinterpret_cast<const int4*>(mask + b * 1024)[tid];
        msk[tid * 4 + 0] = mi.x ? 0.f : -1e9f;
        msk[tid * 4 + 1] = mi.y ? 0.f : -1e9f;
        msk[tid * 4 + 2] = mi.z ? 0.f : -1e9f;
        msk[tid * 4 + 3] = mi.w ? 0.f : -1e9f;
    }

    const bf16* qrow = qkv + (size_t)(b * 1024 + qb * 64 + w * 16 + r) * QKVN + h * 64 + q * 8;
    bf16x8 qf0 = *reinterpret_cast<const bf16x8*>(qrow);
    bf16x8 qf1 = *reinterpret_cast<const bf16x8*>(qrow + 32);

    int csw = (tid & 7) ^ ((tid >> 3) & 7);
    const bf16* kg0 = qkv + (size_t)(b * 1024 + (tid >> 3)) * QKVN + 1024 + h * 64 + csw * 8;
    const bf16* kg1 = kg0 + (size_t)32 * QKVN;
    const bf16* vg0 = Vt + (size_t)((b * 16 + h) * 64 + (tid >> 3)) * 1024 + csw * 8;
    const bf16* vg1 = vg0 + 32 * 1024;
    bf16* kld = &Ks[0][tid * 8];
    bf16* vld = &Vs[0][tid * 8];

    int co0 = (q ^ (r & 7)) * 8;
    bf16* pw = pbuf[w];
    bf16x8 ones;
    #pragma unroll
    for (int jj = 0; jj < 8; ++jj) ones[jj] = (bf16)1.0f;

    float m[4] = {-1e30f, -1e30f, -1e30f, -1e30f};
    f32x4 osum = {};
    f32x4 o[4] = {};

    gl_lds16(kg0, kld);
    gl_lds16(kg1, kld + 2048);
    gl_lds16(vg0, vld);
    gl_lds16(vg1, vld + 2048);

    for (int t = 0; t < 16; ++t) {
        __syncthreads();
        if (t < 15) {
            int ktn = (t + 1) * 64;
            int bo = ((t + 1) & 1) * 4096;
            gl_lds16(kg0 + (size_t)ktn * QKVN, kld + bo);
            gl_lds16(kg1 + (size_t)ktn * QKVN, kld + bo + 2048);
            gl_lds16(vg0 + ktn, vld + bo);
            gl_lds16(vg1 + ktn, vld + bo + 2048);
        }
        const bf16* Kb = Ks[t & 1];
        const bf16* Vb = Vs[t & 1];
        int kt = t * 64;

        f32x4 s[4];
        #pragma unroll
        for (int ks = 0; ks < 4; ++ks) {
            bf16x8 kf0 = *reinterpret_cast<const bf16x8*>(&Kb[(ks * 16 + r) * 64 + co0]);
            bf16x8 kf1 = *reinterpret_cast<const bf16x8*>(&Kb[(ks * 16 + r) * 64 + (co0 ^ 32)]);
            f32x4 a = {};
            a = __builtin_amdgcn_mfma_f32_16x16x32_bf16(qf0, kf0, a, 0, 0, 0);
            a = __builtin_amdgcn_mfma_f32_16x16x32_bf16(qf1, kf1, a, 0, 0, 0);
            float mb = msk[kt + ks * 16 + r];
            #pragma unroll
            for (int i = 0; i < 4; ++i) s[ks][i] = fmaf(a[i], 0.125f, mb);
        }
        float alpha[4];
        #pragma unroll
        for (int i = 0; i < 4; ++i) {
            float t2 = fmaxf(fmaxf(s[0][i], s[1][i]), fmaxf(s[2][i], s[3][i]));
            t2 = fmaxf(t2, __shfl_xor(t2, 1));
            t2 = fmaxf(t2, __shfl_xor(t2, 2));
            t2 = fmaxf(t2, __shfl_xor(t2, 4));
            t2 = fmaxf(t2, __shfl_xor(t2, 8));
            float mn = fmaxf(m[i], t2);
            alpha[i] = __expf(m[i] - mn);
            m[i] = mn;
        }
        #pragma unroll
        for (int i = 0; i < 4; ++i) {
            s[0][i] = __expf(s[0][i] - m[i]);
            s[1][i] = __expf(s[1][i] - m[i]);
            s[2][i] = __expf(s[2][i] - m[i]);
            s[3][i] = __expf(s[3][i] - m[i]);
        }
        #pragma unroll
        for (int i = 0; i < 4; ++i) {
            osum[i] *= alpha[i];
            o[0][i] *= alpha[i]; o[1][i] *= alpha[i];
            o[2][i] *= alpha[i]; o[3][i] *= alpha[i];
        }
        #pragma unroll
        for (int ks = 0; ks < 4; ++ks) {
            int kc = ks * 2 + (r >> 3);
            #pragma unroll
            for (int i = 0; i < 4; ++i) {
                int mr = q * 4 + i;
                pw[mr * 64 + ((kc ^ (mr & 7)) * 8) + (r & 7)] = (bf16)s[ks][i];
            }
        }
        #pragma unroll
        for (int ks2 = 0; ks2 < 2; ++ks2) {
            int vpo = (((ks2 * 4 + q) ^ (r & 7)) * 8);
            bf16x8 pf = *reinterpret_cast<const bf16x8*>(&pw[r * 64 + vpo]);
            #pragma unroll
            for (int nt = 0; nt < 4; ++nt) {
                bf16x8 vf = *reinterpret_cast<const bf16x8*>(&Vb[(nt * 16 + r) * 64 + vpo]);
                o[nt] = __builtin_amdgcn_mfma_f32_16x16x32_bf16(pf, vf, o[nt], 0, 0, 0);
            }
            osum = __builtin_amdgcn_mfma_f32_16x16x32_bf16(pf, ones, osum, 0, 0, 0);
        }
    }

    float inv[4];
    #pragma unroll
    for (int i = 0; i < 4; ++i) inv[i] = 1.0f / osum[i];
    #pragma unroll
    for (int nt = 0; nt < 4; ++nt)
        #pragma unroll
        for (int i = 0; i < 4; ++i)
            out[(size_t)(b * 1024 + qb * 64 + w * 16 + q * 4 + i) * DM + h * 64 + nt * 16 + r] =
                (bf16)(o[nt][i] * inv[i]);
}

// ---------------------------------------------------------------------------
extern "C" void kernel_launch(void* const* d_in, const int* in_sizes, int n_in,
                              void* d_out, int out_size, void* d_ws, size_t ws_size,
                              hipStream_t stream) {
    const float* x      = (const float*)d_in[0];
    const int*   mask   = (const int*)  d_in[1];
    const float* w_q    = (const float*)d_in[2];
    const float* w_k    = (const float*)d_in[3];
    const float* w_v    = (const float*)d_in[4];
    const float* w_o    = (const float*)d_in[5];
    const float* alpha1 = (const float*)d_in[6];
    const float* beta1  = (const float*)d_in[7];
    const float* alpha2 = (const float*)d_in[8];
    const float* beta2  = (const float*)d_in[9];
    const float* fc1_w  = (const float*)d_in[10];
    const float* fc1_b  = (const float*)d_in[11];
    const float* fc2_w  = (const float*)d_in[12];
    const float* fc2_b  = (const float*)d_in[13];
    float* out = (float*)d_out;

    char* ws = (char*)d_ws;
    const size_t MB = 1024 * 1024;
    bf16*  wqkv_b = (bf16*)(ws +  0 * MB);   // 6 MB
    bf16*  wo_b   = (bf16*)(ws +  6 * MB);   // 2 MB
    bf16*  f1w_b  = (bf16*)(ws +  8 * MB);   // 8 MB
    bf16*  f2w_b  = (bf16*)(ws + 16 * MB);   // 8 MB
    bf16*  xn     = (bf16*)(ws + 24 * MB);   // 4 MB
    bf16*  qkvb   = (bf16*)(ws + 28 * MB);   // 12 MB (Q,K; dead after attn)
    bf16*  vtb    = (bf16*)(ws + 40 * MB);   // 4 MB  (dead after attn)
    bf16*  attnb  = (bf16*)(ws + 44 * MB);   // 4 MB  (dead after o-proj)
    float* x2     = (float*)(ws + 48 * MB);  // 8 MB
    float* po     = (float*)(ws + 56 * MB);  // 32 MB o-proj partials (4 slices)
    bf16*  hb     = (bf16*)(ws + 28 * MB);   // 16 MB fc1 out (over qkvb/vtb)
    float* pf2    = (float*)(ws + 56 * MB);  // 32 MB fc2 partials (over po)

    // 1) weights -> bf16 + ln1, one dispatch
    prep_kernel<<<14336, 256, 0, stream>>>(
        (const float4*)w_q, (const float4*)w_k, (const float4*)w_v, (const float4*)w_o,
        (const float4*)fc1_w, (const float4*)fc2_w,
        (bf16x4*)wqkv_b, (bf16x4*)wo_b, (bf16x4*)f1w_b, (bf16x4*)f2w_b,
        x, alpha1, beta1, xn);

    // 2) fused QKV projection (grid 24x16); V-range blocks write vtb
    gemm128<2><<<dim3(24, 16, 1), 256, 0, stream>>>(
        xn, wqkv_b, qkvb, vtb, NTOK, QKVN, DM, DM, 24, 16);

    // 3) flash attention (512 blocks, XCD-swizzled)
    attn_kernel<<<512, 256, 0, stream>>>(qkvb, vtb, mask, attnb);

    // 4) o-proj split-K=4 partials (grid 8x16x4 -> 512 blocks, 2/CU)
    gemm128<4><<<dim3(8, 16, 4), 256, 0, stream>>>(
        attnb, wo_b, po, nullptr, NTOK, DM, DM, DM / 4, 8, 16);

    // 5) reduce + residual -> x2, fused ln2 -> xn
    reduce_ln_kernel<<<NTOK, 256, 0, stream>>>(po, x, alpha2, beta2, x2, xn);

    // 6) fc1 + bias + relu: 128x256 wide tile (grid 16x16 = 256 blocks)
    gemm_wide<1><<<dim3(16, 16, 1), 512, 0, stream>>>(
        xn, f1w_b, hb, fc1_b, NTOK, DFC, DM, DM, 16, 16);

    // 7) fc2: 128x256 wide tile, split-K=4 (grid 4x16x4 = 256 blocks)
    gemm_wide<4><<<dim3(4, 16, 4), 512, 0, stream>>>(
        hb, f2w_b, pf2, nullptr, NTOK, DM, DFC, DFC / 4, 4, 16);

    // 8) bias + residual -> out
    reduce_out_kernel<<<2048, 256, 0, stream>>>(pf2, fc2_b, x2, out);
}

// Round 8
// 246.363 us; speedup vs baseline: 1.2005x; 1.0505x over previous
//
#include <hip/hip_runtime.h>
#include <hip/hip_bf16.h>

// ---------------------------------------------------------------------------
// EncoderBlock round 17:
//  - Budget analysis (r15 per-gemm data + totals): attn ~80us at ~100 TF is
//    the dominant cost (structurally the guide's m166-era 16x16 design).
//  - NEW attn: swapped-QK 32x32 structure (m214-style, re-derived):
//    4 waves x 32 q-rows, mfma_32x32x16(K,Q) -> P lane-local per q-row
//    (C: col=lane&31=qrow, row=(reg&3)+8*(reg>>2)+4*(lane>>5)=kv);
//    in-register online softmax (1 shfl row-max, defer-max THR=8);
//    P->PV fragments via v_cvt_pk_bf16_f32 + shfl_xor(32) half-exchange
//    (no LDS P roundtrip). K/V staging/swizzle/Vt layout unchanged.
//  - Everything else = r12 measured-best structure (2-barrier gemm128,
//    split-K=4 o-proj/fc2, full prep, fused V-transpose in QKV).
// MFMA layouts (verified): 16x16: A[m=lane&15][k=(lane>>4)*8+j],
//   B[k][n=lane&15], C row=(lane>>4)*4+reg, col=lane&15.
//   32x32 C (verified m74/m101): col=lane&31, row=(reg&3)+8*(reg>>2)+4*(lane>>5).
//   32x32 A/B (standard pattern): A[m=lane&31][k=(lane>>5)*8+j], B sym.
// ---------------------------------------------------------------------------

typedef __bf16 bf16;
typedef __attribute__((ext_vector_type(8))) __bf16 bf16x8;
typedef __attribute__((ext_vector_type(4))) __bf16 bf16x4;
typedef __attribute__((ext_vector_type(4))) float f32x4;
typedef __attribute__((ext_vector_type(16))) float f32x16;
typedef __attribute__((ext_vector_type(4))) unsigned int u32x4;

#define NTOK 2048
#define DM   1024
#define DFC  4096
#define QKVN 3072

__device__ inline void gl_lds16(const void* g, void* l) {
    __builtin_amdgcn_global_load_lds((const __attribute__((address_space(1))) void*)g,
                                     (__attribute__((address_space(3))) void*)l, 16, 0, 0);
}

__device__ inline unsigned cvtpk_bf16(float lo, float hi) {
    unsigned r;
    asm("v_cvt_pk_bf16_f32 %0, %1, %2" : "=v"(r) : "v"(lo), "v"(hi));
    return r;
}

// ---------------- LayerNorm row helper (torch: std ddof=1, /(std+eps)) -----
__device__ inline void ln_row(float4 v, const float* alpha, const float* beta,
                              bf16* outrow, int t) {
    float s  = v.x + v.y + v.z + v.w;
    float ss = v.x * v.x + v.y * v.y + v.z * v.z + v.w * v.w;
    __shared__ float red[8];
    int lane = t & 63, wv = t >> 6;
    #pragma unroll
    for (int o = 32; o > 0; o >>= 1) {
        s  += __shfl_down(s, o);
        ss += __shfl_down(ss, o);
    }
    if (lane == 0) { red[wv] = s; red[4 + wv] = ss; }
    __syncthreads();
    float S  = red[0] + red[1] + red[2] + red[3];
    float SS = red[4] + red[5] + red[6] + red[7];
    float mean = S * (1.0f / 1024.0f);
    float var  = (SS - S * mean) * (1.0f / 1023.0f);
    var = var < 0.f ? 0.f : var;
    float inv = 1.0f / (sqrtf(var) + 1e-6f);
    float4 a4 = reinterpret_cast<const float4*>(alpha)[t];
    float4 b4 = reinterpret_cast<const float4*>(beta)[t];
    bf16x4 o4;
    o4[0] = (bf16)(a4.x * (v.x - mean) * inv + b4.x);
    o4[1] = (bf16)(a4.y * (v.y - mean) * inv + b4.y);
    o4[2] = (bf16)(a4.z * (v.z - mean) * inv + b4.z);
    o4[3] = (bf16)(a4.w * (v.w - mean) * inv + b4.w);
    reinterpret_cast<bf16x4*>(outrow)[t] = o4;
}

// ---------------- prep: all weights fp32->bf16 AND ln1, one dispatch --------
__global__ __launch_bounds__(256) void prep_kernel(
    const float4* __restrict__ wq, const float4* __restrict__ wk,
    const float4* __restrict__ wv, const float4* __restrict__ wo,
    const float4* __restrict__ f1, const float4* __restrict__ f2,
    bf16x4* __restrict__ oqkv, bf16x4* __restrict__ oo,
    bf16x4* __restrict__ of1, bf16x4* __restrict__ of2,
    const float* __restrict__ x, const float* __restrict__ alpha1,
    const float* __restrict__ beta1, bf16* __restrict__ xn) {
    int blk = blockIdx.x;
    int t = threadIdx.x;
    if (blk < 12288) {
        int i = blk * 256 + t;
        const int Q = 262144;                        // 1024*1024/4
        float4 v;
        bf16x4* dst;
        if (i < 3 * Q) {
            v = (i < Q) ? wq[i] : (i < 2 * Q) ? wk[i - Q] : wv[i - 2 * Q];
            dst = oqkv + i;
        } else if (i < 4 * Q) {
            v = wo[i - 3 * Q];
            dst = oo + (i - 3 * Q);
        } else if (i < 8 * Q) {
            v = f1[i - 4 * Q];
            dst = of1 + (i - 4 * Q);
        } else {
            v = f2[i - 8 * Q];
            dst = of2 + (i - 8 * Q);
        }
        bf16x4 o;
        o[0] = (bf16)v.x; o[1] = (bf16)v.y; o[2] = (bf16)v.z; o[3] = (bf16)v.w;
        *dst = o;
    } else {
        int row = blk - 12288;
        float4 v = reinterpret_cast<const float4*>(x + (size_t)row * DM)[t];
        ln_row(v, alpha1, beta1, xn + (size_t)row * DM, t);
    }
}

// ---- o-proj split-K=4 reduce + residual -> x2, fused ln2 -> xn (block=row) -
__global__ __launch_bounds__(256) void reduce_ln_kernel(const float* __restrict__ p,
                                                        const float* __restrict__ resid,
                                                        const float* __restrict__ alpha,
                                                        const float* __restrict__ beta,
                                                        float* __restrict__ x2,
                                                        bf16* __restrict__ xn) {
    int row = blockIdx.x, t = threadIdx.x;
    size_t i4 = (size_t)row * 256 + t;
    const size_t SL = 524288;   // M*N/4 float4 per slice
    float4 a = reinterpret_cast<const float4*>(p)[i4];
    float4 b = reinterpret_cast<const float4*>(p)[i4 + SL];
    float4 c = reinterpret_cast<const float4*>(p)[i4 + 2 * SL];
    float4 d = reinterpret_cast<const float4*>(p)[i4 + 3 * SL];
    float4 r = reinterpret_cast<const float4*>(resid)[i4];
    float4 v;
    v.x = a.x + b.x + c.x + d.x + r.x;
    v.y = a.y + b.y + c.y + d.y + r.y;
    v.z = a.z + b.z + c.z + d.z + r.z;
    v.w = a.w + b.w + c.w + d.w + r.w;
    reinterpret_cast<float4*>(x2)[i4] = v;
    ln_row(v, alpha, beta, xn + (size_t)row * DM, t);
}

// ---- fc2 split-K=4 reduce + bias + residual -> d_out (fp32) ----------------
__global__ __launch_bounds__(256) void reduce_out_kernel(const float* __restrict__ p,
                                                         const float* __restrict__ bias,
                                                         const float* __restrict__ x2,
                                                         float* __restrict__ out) {
    size_t i4 = (size_t)blockIdx.x * 256 + threadIdx.x;
    const size_t SL = 524288;
    float4 a = reinterpret_cast<const float4*>(p)[i4];
    float4 b = reinterpret_cast<const float4*>(p)[i4 + SL];
    float4 c = reinterpret_cast<const float4*>(p)[i4 + 2 * SL];
    float4 d = reinterpret_cast<const float4*>(p)[i4 + 3 * SL];
    float4 r = reinterpret_cast<const float4*>(x2)[i4];
    float4 bi = reinterpret_cast<const float4*>(bias)[i4 & 255];
    float4 o;
    o.x = a.x + b.x + c.x + d.x + r.x + bi.x;
    o.y = a.y + b.y + c.y + d.y + r.y + bi.y;
    o.z = a.z + b.z + c.z + d.z + r.z + bi.z;
    o.w = a.w + b.w + c.w + d.w + r.w + bi.w;
    reinterpret_cast<float4*>(out)[i4] = o;
}

// ---------------- GEMM: 128x128 tile, BK=64, dbuf, swizzled LDS (r12) -------
// EPI: 1 = relu(v+bias) bf16; 2 = QKV (V range n0>=2048 -> transposed vt);
//      4 = fp32 partial at z*M*N (split-K).
template <int EPI>
__global__ __launch_bounds__(256) void gemm128(const bf16* __restrict__ A,
                                               const bf16* __restrict__ Bt,
                                               void* __restrict__ outp,
                                               bf16* __restrict__ vt,
                                               const float* __restrict__ bias,
                                               int M, int N, int K, int kslice,
                                               int nbx, int nby) {
    __shared__ bf16 As[2][128 * 64];   // 32 KB
    __shared__ bf16 Bs[2][128 * 64];   // 32 KB
    int tid = threadIdx.x;
    int lane = tid & 63, wave = tid >> 6;
    int q = lane >> 4, r = lane & 15;
    int wm = wave >> 1, wn = wave & 1;

    int lid = blockIdx.y * nbx + blockIdx.x;
    int nxp = nbx >> 3;
    int xcd = lid & 7;
    int loc = lid >> 3;
    int bx = xcd * nxp + (loc % nxp);
    int by = loc / nxp;

    int m0 = by * 128, n0 = bx * 128;
    int kbeg = blockIdx.z * kslice;
    int nit = kslice / 64;
    f32x4 acc[4][4] = {};

    int srow = tid >> 3;
    int csrc = (tid & 7) ^ (srow & 7);
    const bf16* agp = A  + (size_t)(m0 + srow) * K + kbeg + csrc * 8;
    const bf16* bgp = Bt + (size_t)(n0 + srow) * K + kbeg + csrc * 8;

    int co0 = ((q ^ (r & 7)) * 8);
    int co1 = co0 ^ 32;
    int aoff = (wm * 64 + r) * 64;
    int boff = (wn * 64 + r) * 64;

    auto stage = [&](int it, int b) {
        int k0 = it * 64;
        #pragma unroll
        for (int j = 0; j < 4; ++j) {
            gl_lds16(agp + (size_t)j * 32 * K + k0, &As[b][tid * 8 + j * 2048]);
            gl_lds16(bgp + (size_t)j * 32 * K + k0, &Bs[b][tid * 8 + j * 2048]);
        }
    };

    stage(0, 0);
    for (int it = 0; it < nit; ++it) {
        __syncthreads();                       // drains stage(it)
        if (it + 1 < nit) stage(it + 1, (it + 1) & 1);
        const bf16* Ab = &As[it & 1][aoff];
        const bf16* Bb = &Bs[it & 1][boff];
        #pragma unroll
        for (int half = 0; half < 2; ++half) {
            int co = half ? co1 : co0;
            bf16x8 af[4], bfv[4];
            #pragma unroll
            for (int t = 0; t < 4; ++t)
                af[t] = *reinterpret_cast<const bf16x8*>(Ab + t * 1024 + co);
            #pragma unroll
            for (int u = 0; u < 4; ++u)
                bfv[u] = *reinterpret_cast<const bf16x8*>(Bb + u * 1024 + co);
            #pragma unroll
            for (int t = 0; t < 4; ++t)
                #pragma unroll
                for (int u = 0; u < 4; ++u)
                    acc[t][u] = __builtin_amdgcn_mfma_f32_16x16x32_bf16(af[t], bfv[u], acc[t][u], 0, 0, 0);
        }
    }

    if (EPI == 2 && n0 >= 2048) {
        int bb = m0 >> 10;
        int sb = (m0 & 1023) + wm * 64 + q * 4;
        int vrow0 = bb * 1024 + (n0 - 2048) + wn * 64;
        #pragma unroll
        for (int t = 0; t < 4; ++t) {
            #pragma unroll
            for (int u = 0; u < 4; ++u) {
                bf16x4 pk;
                #pragma unroll
                for (int i = 0; i < 4; ++i) pk[i] = (bf16)acc[t][u][i];
                *reinterpret_cast<bf16x4*>(vt + (size_t)(vrow0 + u * 16 + r) * 1024 + sb + t * 16) = pk;
            }
        }
        return;
    }

    size_t zoff = (size_t)blockIdx.z * M * N;
    #pragma unroll
    for (int t = 0; t < 4; ++t) {
        #pragma unroll
        for (int u = 0; u < 4; ++u) {
            #pragma unroll
            for (int i = 0; i < 4; ++i) {
                int mm = m0 + wm * 64 + t * 16 + q * 4 + i;
                int nn = n0 + wn * 64 + u * 16 + r;
                size_t idx = (size_t)mm * N + nn;
                float v = acc[t][u][i];
                if (EPI == 1) {
                    v += bias[nn];
                    ((bf16*)outp)[idx] = (bf16)(v > 0.f ? v : 0.f);
                } else if (EPI == 2) {
                    ((bf16*)outp)[idx] = (bf16)v;
                } else {
                    ((float*)outp)[zoff + idx] = v;
                }
            }
        }
    }
}

// ---------------- flash attention: swapped-QK 32x32, in-register softmax ----
// 4 waves x 32 q-rows = 128 q-rows/block; grid 256 (8 q-tiles x 32 bh).
// QK: s = mfma_32x32x16(K-frag, Q-frag) chained over 4 k-steps ->
//   lane holds P[qrow=lane&31][kv=(reg&3)+8*(reg>>2)+4*(lane>>5)] per 32-tile.
// Softmax: per-lane over 32 vals + 1 shfl_xor(32); defer-max THR=8 (rescale
//   path does an LDS alpha bounce for the (reg,hi)-row O accumulator).
// PV: A-frag P[qrow=lane&31][k=(lane>>5)*8+j] assembled via cvt_pk + 1
//   shfl_xor(32) half-exchange; B-frag = V^T rows from Vs (swizzled).
__global__ __launch_bounds__(256) void attn_kernel(const bf16* __restrict__ qkv,
                                                   const bf16* __restrict__ Vt,
                                                   const int* __restrict__ mask,
                                                   bf16* __restrict__ out) {
    __shared__ bf16 Ks[2][4096];     // 16 KB
    __shared__ bf16 Vs[2][4096];     // 16 KB
    __shared__ float msk[1024];      // 4 KB
    __shared__ float als[4][32];     // 512 B  (per-wave alpha / 1/l bounce)
    int tid = threadIdx.x;
    int lane = tid & 63, w = tid >> 6;
    int l5 = lane & 31, hi = lane >> 5;

    int id = blockIdx.x;
    int xcd = id & 7, jj = id >> 3;      // jj in [0,32)
    int bh = xcd * 4 + (jj >> 3);        // [0,32)
    int qb = jj & 7;                     // 8 q-tiles of 128 rows
    int b = bh >> 4, h = bh & 15;

    {
        int4 mi = reinterpret_cast<const int4*>(mask + b * 1024)[tid];
        msk[tid * 4 + 0] = mi.x ? 0.f : -1e9f;
        msk[tid * 4 + 1] = mi.y ? 0.f : -1e9f;
        msk[tid * 4 + 2] = mi.z ? 0.f : -1e9f;
        msk[tid * 4 + 3] = mi.w ? 0.f : -1e9f;
    }

    int qrow0 = qb * 128 + w * 32;
    // Q fragment: B[k=(lane>>5)*8+j][n=qrow=l5]; d = ks*16 + hi*8 + j
    const bf16* qp = qkv + (size_t)(b * 1024 + qrow0 + l5) * QKVN + h * 64 + hi * 8;
    bf16x8 qf[4];
    #pragma unroll
    for (int ks = 0; ks < 4; ++ks)
        qf[ks] = *reinterpret_cast<const bf16x8*>(qp + ks * 16);

    // staging (identical scheme to verified r8-r16 kernel)
    int csw = (tid & 7) ^ ((tid >> 3) & 7);
    const bf16* kg0 = qkv + (size_t)(b * 1024 + (tid >> 3)) * QKVN + 1024 + h * 64 + csw * 8;
    const bf16* kg1 = kg0 + (size_t)32 * QKVN;
    const bf16* vg0 = Vt + (size_t)((b * 16 + h) * 64 + (tid >> 3)) * 1024 + csw * 8;
    const bf16* vg1 = vg0 + 32 * 1024;
    bf16* kld = &Ks[0][tid * 8];
    bf16* vld = &Vs[0][tid * 8];

    gl_lds16(kg0, kld);
    gl_lds16(kg1, kld + 2048);
    gl_lds16(vg0, vld);
    gl_lds16(vg1, vld + 2048);

    float m_run = -1e30f, l_half = 0.f;
    f32x16 o0 = {};      // d = l5       (dtile 0)
    f32x16 o1 = {};      // d = 32 + l5  (dtile 1)

    for (int t = 0; t < 16; ++t) {
        __syncthreads();
        if (t < 15) {
            int ktn = (t + 1) * 64;
            int bo = ((t + 1) & 1) * 4096;
            gl_lds16(kg0 + (size_t)ktn * QKVN, kld + bo);
            gl_lds16(kg1 + (size_t)ktn * QKVN, kld + bo + 2048);
            gl_lds16(vg0 + ktn, vld + bo);
            gl_lds16(vg1 + ktn, vld + bo + 2048);
        }
        const bf16* Kb = Ks[t & 1];
        const bf16* Vb = Vs[t & 1];
        int kt = t * 64;

        // QK^T (swapped): two 32-kv tiles
        f32x16 s0 = {}, s1 = {};
        __builtin_amdgcn_s_setprio(1);
        #pragma unroll
        for (int ks = 0; ks < 4; ++ks) {
            int ch = (((ks << 1) + hi) ^ (l5 & 7)) << 3;
            bf16x8 k0 = *reinterpret_cast<const bf16x8*>(&Kb[l5 * 64 + ch]);
            bf16x8 k1 = *reinterpret_cast<const bf16x8*>(&Kb[(32 + l5) * 64 + ch]);
            s0 = __builtin_amdgcn_mfma_f32_32x32x16_bf16(k0, qf[ks], s0, 0, 0, 0);
            s1 = __builtin_amdgcn_mfma_f32_32x32x16_bf16(k1, qf[ks], s1, 0, 0, 0);
        }
        __builtin_amdgcn_s_setprio(0);

        // scale + mask + row max (per-lane rows!)
        float p0[16], p1[16];
        float pmax = -1e30f;
        #pragma unroll
        for (int g = 0; g < 4; ++g) {
            float4 mb0 = *reinterpret_cast<const float4*>(&msk[kt + g * 8 + hi * 4]);
            float4 mb1 = *reinterpret_cast<const float4*>(&msk[kt + 32 + g * 8 + hi * 4]);
            #pragma unroll
            for (int i = 0; i < 4; ++i) {
                float mbv0 = (i == 0) ? mb0.x : (i == 1) ? mb0.y : (i == 2) ? mb0.z : mb0.w;
                float mbv1 = (i == 0) ? mb1.x : (i == 1) ? mb1.y : (i == 2) ? mb1.z : mb1.w;
                float a0 = fmaf(s0[g * 4 + i], 0.125f, mbv0);
                float a1 = fmaf(s1[g * 4 + i], 0.125f, mbv1);
                p0[g * 4 + i] = a0;
                p1[g * 4 + i] = a1;
                pmax = fmaxf(pmax, fmaxf(a0, a1));
            }
        }
        pmax = fmaxf(pmax, __shfl_xor(pmax, 32));
        float mnew = fmaxf(m_run, pmax);
        if (!__all(pmax - m_run <= 8.0f)) {          // defer-max (T13)
            float alpha = __expf(m_run - mnew);
            m_run = mnew;
            l_half *= alpha;
            als[w][l5] = alpha;                       // both hi lanes write same
            #pragma unroll
            for (int g = 0; g < 4; ++g) {
                float4 av = *reinterpret_cast<const float4*>(&als[w][g * 8 + hi * 4]);
                o0[g * 4 + 0] *= av.x; o0[g * 4 + 1] *= av.y;
                o0[g * 4 + 2] *= av.z; o0[g * 4 + 3] *= av.w;
                o1[g * 4 + 0] *= av.x; o1[g * 4 + 1] *= av.y;
                o1[g * 4 + 2] *= av.z; o1[g * 4 + 3] *= av.w;
            }
        }
        float sum = 0.f;
        #pragma unroll
        for (int rg = 0; rg < 16; ++rg) {
            p0[rg] = __expf(p0[rg] - m_run);
            p1[rg] = __expf(p1[rg] - m_run);
            sum += p0[rg] + p1[rg];
        }
        l_half += sum;

        // PV: per 32-kv tile, per 16-kv k-step: assemble pf + 2 d-tiles
        __builtin_amdgcn_s_setprio(1);
        #pragma unroll
        for (int tile = 0; tile < 2; ++tile) {
            const float* pp = tile ? p1 : p0;
            #pragma unroll
            for (int kp = 0; kp < 2; ++kp) {
                // packs: A-base = p[8kp..], B-base = p[8kp+4..]  (compile-time idx)
                unsigned uA0 = cvtpk_bf16(pp[8 * kp + 0], pp[8 * kp + 1]);
                unsigned uA1 = cvtpk_bf16(pp[8 * kp + 2], pp[8 * kp + 3]);
                unsigned uB0 = cvtpk_bf16(pp[8 * kp + 4], pp[8 * kp + 5]);
                unsigned uB1 = cvtpk_bf16(pp[8 * kp + 6], pp[8 * kp + 7]);
                unsigned us0 = hi ? uB0 : uA0, us1 = hi ? uB1 : uA1;  // self part
                unsigned ug0 = hi ? uA0 : uB0, ug1 = hi ? uA1 : uB1;  // give part
                unsigned r0 = (unsigned)__shfl_xor((int)ug0, 32);
                unsigned r1 = (unsigned)__shfl_xor((int)ug1, 32);
                u32x4 pw_;
                pw_[0] = hi ? r0 : us0;
                pw_[1] = hi ? r1 : us1;
                pw_[2] = hi ? us0 : r0;
                pw_[3] = hi ? us1 : r1;
                bf16x8 pf = *reinterpret_cast<bf16x8*>(&pw_);
                int vch = (((tile << 2) + (kp << 1) + hi) ^ (l5 & 7)) << 3;
                bf16x8 v0 = *reinterpret_cast<const bf16x8*>(&Vb[l5 * 64 + vch]);
                bf16x8 v1 = *reinterpret_cast<const bf16x8*>(&Vb[(32 + l5) * 64 + vch]);
                o0 = __builtin_amdgcn_mfma_f32_32x32x16_bf16(pf, v0, o0, 0, 0, 0);
                o1 = __builtin_amdgcn_mfma_f32_32x32x16_bf16(pf, v1, o1, 0, 0, 0);
            }
        }
        __builtin_amdgcn_s_setprio(0);
    }

    // epilogue: combine halves of l, bounce 1/l, normalize, store
    float l_tot = l_half + __shfl_xor(l_half, 32);
    als[w][l5] = 1.0f / l_tot;
    bf16* ob = out + (size_t)(b * 1024 + qrow0) * DM + h * 64;
    #pragma unroll
    for (int g = 0; g < 4; ++g) {
        float4 iv = *reinterpret_cast<const float4*>(&als[w][g * 8 + hi * 4]);
        #pragma unroll
        for (int i = 0; i < 4; ++i) {
            float ivv = (i == 0) ? iv.x : (i == 1) ? iv.y : (i == 2) ? iv.z : iv.w;
            int qr = g * 8 + hi * 4 + i;
            ob[(size_t)qr * DM + l5]      = (bf16)(o0[g * 4 + i] * ivv);
            ob[(size_t)qr * DM + 32 + l5] = (bf16)(o1[g * 4 + i] * ivv);
        }
    }
}

// ---------------------------------------------------------------------------
extern "C" void kernel_launch(void* const* d_in, const int* in_sizes, int n_in,
                              void* d_out, int out_size, void* d_ws, size_t ws_size,
                              hipStream_t stream) {
    const float* x      = (const float*)d_in[0];
    const int*   mask   = (const int*)  d_in[1];
    const float* w_q    = (const float*)d_in[2];
    const float* w_k    = (const float*)d_in[3];
    const float* w_v    = (const float*)d_in[4];
    const float* w_o    = (const float*)d_in[5];
    const float* alpha1 = (const float*)d_in[6];
    const float* beta1  = (const float*)d_in[7];
    const float* alpha2 = (const float*)d_in[8];
    const float* beta2  = (const float*)d_in[9];
    const float* fc1_w  = (const float*)d_in[10];
    const float* fc1_b  = (const float*)d_in[11];
    const float* fc2_w  = (const float*)d_in[12];
    const float* fc2_b  = (const float*)d_in[13];
    float* out = (float*)d_out;

    char* ws = (char*)d_ws;
    const size_t MB = 1024 * 1024;
    bf16*  wqkv_b = (bf16*)(ws +  0 * MB);   // 6 MB
    bf16*  wo_b   = (bf16*)(ws +  6 * MB);   // 2 MB
    bf16*  f1w_b  = (bf16*)(ws +  8 * MB);   // 8 MB
    bf16*  f2w_b  = (bf16*)(ws + 16 * MB);   // 8 MB
    bf16*  xn     = (bf16*)(ws + 24 * MB);   // 4 MB
    bf16*  qkvb   = (bf16*)(ws + 28 * MB);   // 12 MB (Q,K; dead after attn)
    bf16*  vtb    = (bf16*)(ws + 40 * MB);   // 4 MB  (dead after attn)
    bf16*  attnb  = (bf16*)(ws + 44 * MB);   // 4 MB  (dead after o-proj)
    float* x2     = (float*)(ws + 48 * MB);  // 8 MB
    float* po     = (float*)(ws + 56 * MB);  // 32 MB o-proj partials (4 slices)
    bf16*  hb     = (bf16*)(ws + 28 * MB);   // 16 MB fc1 out (over qkvb/vtb)
    float* pf2    = (float*)(ws + 56 * MB);  // 32 MB fc2 partials (over po)

    // 1) weights -> bf16 + ln1, one dispatch
    prep_kernel<<<14336, 256, 0, stream>>>(
        (const float4*)w_q, (const float4*)w_k, (const float4*)w_v, (const float4*)w_o,
        (const float4*)fc1_w, (const float4*)fc2_w,
        (bf16x4*)wqkv_b, (bf16x4*)wo_b, (bf16x4*)f1w_b, (bf16x4*)f2w_b,
        x, alpha1, beta1, xn);

    // 2) fused QKV projection (grid 24x16); V-range blocks write vtb
    gemm128<2><<<dim3(24, 16, 1), 256, 0, stream>>>(
        xn, wqkv_b, qkvb, vtb, nullptr, NTOK, QKVN, DM, DM, 24, 16);

    // 3) flash attention (256 blocks, XCD-swizzled, swapped-QK 32x32)
    attn_kernel<<<256, 256, 0, stream>>>(qkvb, vtb, mask, attnb);

    // 4) o-proj split-K=4 partials (grid 8x16x4 -> 512 blocks, 2/CU)
    gemm128<4><<<dim3(8, 16, 4), 256, 0, stream>>>(
        attnb, wo_b, po, nullptr, nullptr, NTOK, DM, DM, DM / 4, 8, 16);

    // 5) reduce + residual -> x2, fused ln2 -> xn
    reduce_ln_kernel<<<NTOK, 256, 0, stream>>>(po, x, alpha2, beta2, x2, xn);

    // 6) fc1 + bias + relu (grid 32x16)
    gemm128<1><<<dim3(32, 16, 1), 256, 0, stream>>>(
        xn, f1w_b, hb, nullptr, fc1_b, NTOK, DFC, DM, DM, 32, 16);

    // 7) fc2 split-K=4 partials (grid 8x16x4 -> 512 blocks, 2/CU)
    gemm128<4><<<dim3(8, 16, 4), 256, 0, stream>>>(
        hb, f2w_b, pf2, nullptr, nullptr, NTOK, DM, DFC, DFC / 4, 8, 16);

    // 8) bias + residual -> out
    reduce_out_kernel<<<2048, 256, 0, stream>>>(pf2, fc2_b, x2, out);
}

// Round 9
// 239.284 us; speedup vs baseline: 1.2361x; 1.0296x over previous
//
#include <hip/hip_runtime.h>
#include <hip/hip_bf16.h>

// ---------------------------------------------------------------------------
// EncoderBlock round 18:
//  - r17 win kept: swapped-QK 32x32 attn (246.4us, best).
//  - NEW: wo/fc1/fc2 fp32->bf16 conversion moved to 2304 TRAILING BLOCKS of
//    the ATTN dispatch (attn LDS = 36.5KB -> conv blocks co-schedule at
//    3-4/CU, unlike r11's failed QKV-overlap at 64KB/2 per CU). Attn is
//    1 block/CU + ~25% HBM -> slots and BW are idle. prep slims to
//    wqkv conversion + ln1 (5120 blocks, ~34MB).
//  - GEMMs/reduces: r12 measured-best structure, untouched (6 structural
//    attempts all null/regressed - latency-bound plateau accepted).
// MFMA layouts (verified): 16x16: A[m=lane&15][k=(lane>>4)*8+j],
//   B[k][n=lane&15], C row=(lane>>4)*4+reg, col=lane&15.
//   32x32 C (verified): col=lane&31, row=(reg&3)+8*(reg>>2)+4*(lane>>5).
//   32x32 A/B: A[m=lane&31][k=(lane>>5)*8+j], B sym. (r17 refcheck passed)
// ---------------------------------------------------------------------------

typedef __bf16 bf16;
typedef __attribute__((ext_vector_type(8))) __bf16 bf16x8;
typedef __attribute__((ext_vector_type(4))) __bf16 bf16x4;
typedef __attribute__((ext_vector_type(4))) float f32x4;
typedef __attribute__((ext_vector_type(16))) float f32x16;
typedef __attribute__((ext_vector_type(4))) unsigned int u32x4;

#define NTOK 2048
#define DM   1024
#define DFC  4096
#define QKVN 3072

__device__ inline void gl_lds16(const void* g, void* l) {
    __builtin_amdgcn_global_load_lds((const __attribute__((address_space(1))) void*)g,
                                     (__attribute__((address_space(3))) void*)l, 16, 0, 0);
}

__device__ inline unsigned cvtpk_bf16(float lo, float hi) {
    unsigned r;
    asm("v_cvt_pk_bf16_f32 %0, %1, %2" : "=v"(r) : "v"(lo), "v"(hi));
    return r;
}

// ---------------- LayerNorm row helper (torch: std ddof=1, /(std+eps)) -----
__device__ inline void ln_row(float4 v, const float* alpha, const float* beta,
                              bf16* outrow, int t) {
    float s  = v.x + v.y + v.z + v.w;
    float ss = v.x * v.x + v.y * v.y + v.z * v.z + v.w * v.w;
    __shared__ float red[8];
    int lane = t & 63, wv = t >> 6;
    #pragma unroll
    for (int o = 32; o > 0; o >>= 1) {
        s  += __shfl_down(s, o);
        ss += __shfl_down(ss, o);
    }
    if (lane == 0) { red[wv] = s; red[4 + wv] = ss; }
    __syncthreads();
    float S  = red[0] + red[1] + red[2] + red[3];
    float SS = red[4] + red[5] + red[6] + red[7];
    float mean = S * (1.0f / 1024.0f);
    float var  = (SS - S * mean) * (1.0f / 1023.0f);
    var = var < 0.f ? 0.f : var;
    float inv = 1.0f / (sqrtf(var) + 1e-6f);
    float4 a4 = reinterpret_cast<const float4*>(alpha)[t];
    float4 b4 = reinterpret_cast<const float4*>(beta)[t];
    bf16x4 o4;
    o4[0] = (bf16)(a4.x * (v.x - mean) * inv + b4.x);
    o4[1] = (bf16)(a4.y * (v.y - mean) * inv + b4.y);
    o4[2] = (bf16)(a4.z * (v.z - mean) * inv + b4.z);
    o4[3] = (bf16)(a4.w * (v.w - mean) * inv + b4.w);
    reinterpret_cast<bf16x4*>(outrow)[t] = o4;
}

// ---------------- prep: wqkv fp32->bf16 AND ln1 -----------------------------
__global__ __launch_bounds__(256) void prep_kernel(
    const float4* __restrict__ wq, const float4* __restrict__ wk,
    const float4* __restrict__ wv, bf16x4* __restrict__ oqkv,
    const float* __restrict__ x, const float* __restrict__ alpha1,
    const float* __restrict__ beta1, bf16* __restrict__ xn) {
    int blk = blockIdx.x;
    int t = threadIdx.x;
    if (blk < 3072) {
        int i = blk * 256 + t;
        const int Q = 262144;                        // 1024*1024/4
        float4 v = (i < Q) ? wq[i] : (i < 2 * Q) ? wk[i - Q] : wv[i - 2 * Q];
        bf16x4 o;
        o[0] = (bf16)v.x; o[1] = (bf16)v.y; o[2] = (bf16)v.z; o[3] = (bf16)v.w;
        oqkv[i] = o;
    } else {
        int row = blk - 3072;
        float4 v = reinterpret_cast<const float4*>(x + (size_t)row * DM)[t];
        ln_row(v, alpha1, beta1, xn + (size_t)row * DM, t);
    }
}

// ---- o-proj split-K=4 reduce + residual -> x2, fused ln2 -> xn (block=row) -
__global__ __launch_bounds__(256) void reduce_ln_kernel(const float* __restrict__ p,
                                                        const float* __restrict__ resid,
                                                        const float* __restrict__ alpha,
                                                        const float* __restrict__ beta,
                                                        float* __restrict__ x2,
                                                        bf16* __restrict__ xn) {
    int row = blockIdx.x, t = threadIdx.x;
    size_t i4 = (size_t)row * 256 + t;
    const size_t SL = 524288;   // M*N/4 float4 per slice
    float4 a = reinterpret_cast<const float4*>(p)[i4];
    float4 b = reinterpret_cast<const float4*>(p)[i4 + SL];
    float4 c = reinterpret_cast<const float4*>(p)[i4 + 2 * SL];
    float4 d = reinterpret_cast<const float4*>(p)[i4 + 3 * SL];
    float4 r = reinterpret_cast<const float4*>(resid)[i4];
    float4 v;
    v.x = a.x + b.x + c.x + d.x + r.x;
    v.y = a.y + b.y + c.y + d.y + r.y;
    v.z = a.z + b.z + c.z + d.z + r.z;
    v.w = a.w + b.w + c.w + d.w + r.w;
    reinterpret_cast<float4*>(x2)[i4] = v;
    ln_row(v, alpha, beta, xn + (size_t)row * DM, t);
}

// ---- fc2 split-K=4 reduce + bias + residual -> d_out (fp32) ----------------
__global__ __launch_bounds__(256) void reduce_out_kernel(const float* __restrict__ p,
                                                         const float* __restrict__ bias,
                                                         const float* __restrict__ x2,
                                                         float* __restrict__ out) {
    size_t i4 = (size_t)blockIdx.x * 256 + threadIdx.x;
    const size_t SL = 524288;
    float4 a = reinterpret_cast<const float4*>(p)[i4];
    float4 b = reinterpret_cast<const float4*>(p)[i4 + SL];
    float4 c = reinterpret_cast<const float4*>(p)[i4 + 2 * SL];
    float4 d = reinterpret_cast<const float4*>(p)[i4 + 3 * SL];
    float4 r = reinterpret_cast<const float4*>(x2)[i4];
    float4 bi = reinterpret_cast<const float4*>(bias)[i4 & 255];
    float4 o;
    o.x = a.x + b.x + c.x + d.x + r.x + bi.x;
    o.y = a.y + b.y + c.y + d.y + r.y + bi.y;
    o.z = a.z + b.z + c.z + d.z + r.z + bi.z;
    o.w = a.w + b.w + c.w + d.w + r.w + bi.w;
    reinterpret_cast<float4*>(out)[i4] = o;
}

// ---------------- GEMM: 128x128 tile, BK=64, dbuf, swizzled LDS (r12) -------
// EPI: 1 = relu(v+bias) bf16; 2 = QKV (V range n0>=2048 -> transposed vt);
//      4 = fp32 partial at z*M*N (split-K).
template <int EPI>
__global__ __launch_bounds__(256) void gemm128(const bf16* __restrict__ A,
                                               const bf16* __restrict__ Bt,
                                               void* __restrict__ outp,
                                               bf16* __restrict__ vt,
                                               const float* __restrict__ bias,
                                               int M, int N, int K, int kslice,
                                               int nbx, int nby) {
    __shared__ bf16 As[2][128 * 64];   // 32 KB
    __shared__ bf16 Bs[2][128 * 64];   // 32 KB
    int tid = threadIdx.x;
    int lane = tid & 63, wave = tid >> 6;
    int q = lane >> 4, r = lane & 15;
    int wm = wave >> 1, wn = wave & 1;

    int lid = blockIdx.y * nbx + blockIdx.x;
    int nxp = nbx >> 3;
    int xcd = lid & 7;
    int loc = lid >> 3;
    int bx = xcd * nxp + (loc % nxp);
    int by = loc / nxp;

    int m0 = by * 128, n0 = bx * 128;
    int kbeg = blockIdx.z * kslice;
    int nit = kslice / 64;
    f32x4 acc[4][4] = {};

    int srow = tid >> 3;
    int csrc = (tid & 7) ^ (srow & 7);
    const bf16* agp = A  + (size_t)(m0 + srow) * K + kbeg + csrc * 8;
    const bf16* bgp = Bt + (size_t)(n0 + srow) * K + kbeg + csrc * 8;

    int co0 = ((q ^ (r & 7)) * 8);
    int co1 = co0 ^ 32;
    int aoff = (wm * 64 + r) * 64;
    int boff = (wn * 64 + r) * 64;

    auto stage = [&](int it, int b) {
        int k0 = it * 64;
        #pragma unroll
        for (int j = 0; j < 4; ++j) {
            gl_lds16(agp + (size_t)j * 32 * K + k0, &As[b][tid * 8 + j * 2048]);
            gl_lds16(bgp + (size_t)j * 32 * K + k0, &Bs[b][tid * 8 + j * 2048]);
        }
    };

    stage(0, 0);
    for (int it = 0; it < nit; ++it) {
        __syncthreads();                       // drains stage(it)
        if (it + 1 < nit) stage(it + 1, (it + 1) & 1);
        const bf16* Ab = &As[it & 1][aoff];
        const bf16* Bb = &Bs[it & 1][boff];
        #pragma unroll
        for (int half = 0; half < 2; ++half) {
            int co = half ? co1 : co0;
            bf16x8 af[4], bfv[4];
            #pragma unroll
            for (int t = 0; t < 4; ++t)
                af[t] = *reinterpret_cast<const bf16x8*>(Ab + t * 1024 + co);
            #pragma unroll
            for (int u = 0; u < 4; ++u)
                bfv[u] = *reinterpret_cast<const bf16x8*>(Bb + u * 1024 + co);
            #pragma unroll
            for (int t = 0; t < 4; ++t)
                #pragma unroll
                for (int u = 0; u < 4; ++u)
                    acc[t][u] = __builtin_amdgcn_mfma_f32_16x16x32_bf16(af[t], bfv[u], acc[t][u], 0, 0, 0);
        }
    }

    if (EPI == 2 && n0 >= 2048) {
        int bb = m0 >> 10;
        int sb = (m0 & 1023) + wm * 64 + q * 4;
        int vrow0 = bb * 1024 + (n0 - 2048) + wn * 64;
        #pragma unroll
        for (int t = 0; t < 4; ++t) {
            #pragma unroll
            for (int u = 0; u < 4; ++u) {
                bf16x4 pk;
                #pragma unroll
                for (int i = 0; i < 4; ++i) pk[i] = (bf16)acc[t][u][i];
                *reinterpret_cast<bf16x4*>(vt + (size_t)(vrow0 + u * 16 + r) * 1024 + sb + t * 16) = pk;
            }
        }
        return;
    }

    size_t zoff = (size_t)blockIdx.z * M * N;
    #pragma unroll
    for (int t = 0; t < 4; ++t) {
        #pragma unroll
        for (int u = 0; u < 4; ++u) {
            #pragma unroll
            for (int i = 0; i < 4; ++i) {
                int mm = m0 + wm * 64 + t * 16 + q * 4 + i;
                int nn = n0 + wn * 64 + u * 16 + r;
                size_t idx = (size_t)mm * N + nn;
                float v = acc[t][u][i];
                if (EPI == 1) {
                    v += bias[nn];
                    ((bf16*)outp)[idx] = (bf16)(v > 0.f ? v : 0.f);
                } else if (EPI == 2) {
                    ((bf16*)outp)[idx] = (bf16)v;
                } else {
                    ((float*)outp)[zoff + idx] = v;
                }
            }
        }
    }
}

// ---------------- flash attention: swapped-QK 32x32, in-register softmax ----
// Blocks [0,256): attn (r17, refcheck'd). Blocks [256,2560): wo/fc1/fc2
// fp32->bf16 conversion (64B/thread), co-scheduled in attn's idle CU slots
// (attn = 36.5KB LDS, 1 block/CU -> conv blocks fill remaining occupancy).
__global__ __launch_bounds__(256) void attn_kernel(const bf16* __restrict__ qkv,
                                                   const bf16* __restrict__ Vt,
                                                   const int* __restrict__ mask,
                                                   bf16* __restrict__ out,
                                                   const float4* __restrict__ cwo,
                                                   const float4* __restrict__ cf1,
                                                   const float4* __restrict__ cf2,
                                                   bf16x4* __restrict__ oo,
                                                   bf16x4* __restrict__ of1,
                                                   bf16x4* __restrict__ of2) {
    __shared__ bf16 Ks[2][4096];     // 16 KB
    __shared__ bf16 Vs[2][4096];     // 16 KB
    __shared__ float msk[1024];      // 4 KB
    __shared__ float als[4][32];     // 512 B
    int tid = threadIdx.x;

    if (blockIdx.x >= 256) {         // ---- weight-conversion trailing blocks
        int base = (blockIdx.x - 256) * 1024;       // float4 units, 1024/block
        const int Q = 262144;                       // 1024*1024/4 float4
        #pragma unroll
        for (int k = 0; k < 4; ++k) {
            int i = base + k * 256 + tid;
            float4 v;
            bf16x4* dst;
            if (i < Q)          { v = cwo[i];         dst = oo  + i; }
            else if (i < 5 * Q) { v = cf1[i - Q];     dst = of1 + (i - Q); }
            else                { v = cf2[i - 5 * Q]; dst = of2 + (i - 5 * Q); }
            bf16x4 o;
            o[0] = (bf16)v.x; o[1] = (bf16)v.y; o[2] = (bf16)v.z; o[3] = (bf16)v.w;
            *dst = o;
        }
        return;
    }

    int lane = tid & 63, w = tid >> 6;
    int l5 = lane & 31, hi = lane >> 5;

    int id = blockIdx.x;
    int xcd = id & 7, jj = id >> 3;      // jj in [0,32)
    int bh = xcd * 4 + (jj >> 3);        // [0,32)
    int qb = jj & 7;                     // 8 q-tiles of 128 rows
    int b = bh >> 4, h = bh & 15;

    {
        int4 mi = reinterpret_cast<const int4*>(mask + b * 1024)[tid];
        msk[tid * 4 + 0] = mi.x ? 0.f : -1e9f;
        msk[tid * 4 + 1] = mi.y ? 0.f : -1e9f;
        msk[tid * 4 + 2] = mi.z ? 0.f : -1e9f;
        msk[tid * 4 + 3] = mi.w ? 0.f : -1e9f;
    }

    int qrow0 = qb * 128 + w * 32;
    const bf16* qp = qkv + (size_t)(b * 1024 + qrow0 + l5) * QKVN + h * 64 + hi * 8;
    bf16x8 qf[4];
    #pragma unroll
    for (int ks = 0; ks < 4; ++ks)
        qf[ks] = *reinterpret_cast<const bf16x8*>(qp + ks * 16);

    int csw = (tid & 7) ^ ((tid >> 3) & 7);
    const bf16* kg0 = qkv + (size_t)(b * 1024 + (tid >> 3)) * QKVN + 1024 + h * 64 + csw * 8;
    const bf16* kg1 = kg0 + (size_t)32 * QKVN;
    const bf16* vg0 = Vt + (size_t)((b * 16 + h) * 64 + (tid >> 3)) * 1024 + csw * 8;
    const bf16* vg1 = vg0 + 32 * 1024;
    bf16* kld = &Ks[0][tid * 8];
    bf16* vld = &Vs[0][tid * 8];

    gl_lds16(kg0, kld);
    gl_lds16(kg1, kld + 2048);
    gl_lds16(vg0, vld);
    gl_lds16(vg1, vld + 2048);

    float m_run = -1e30f, l_half = 0.f;
    f32x16 o0 = {};      // d = l5
    f32x16 o1 = {};      // d = 32 + l5

    for (int t = 0; t < 16; ++t) {
        __syncthreads();
        if (t < 15) {
            int ktn = (t + 1) * 64;
            int bo = ((t + 1) & 1) * 4096;
            gl_lds16(kg0 + (size_t)ktn * QKVN, kld + bo);
            gl_lds16(kg1 + (size_t)ktn * QKVN, kld + bo + 2048);
            gl_lds16(vg0 + ktn, vld + bo);
            gl_lds16(vg1 + ktn, vld + bo + 2048);
        }
        const bf16* Kb = Ks[t & 1];
        const bf16* Vb = Vs[t & 1];
        int kt = t * 64;

        f32x16 s0 = {}, s1 = {};
        __builtin_amdgcn_s_setprio(1);
        #pragma unroll
        for (int ks = 0; ks < 4; ++ks) {
            int ch = (((ks << 1) + hi) ^ (l5 & 7)) << 3;
            bf16x8 k0 = *reinterpret_cast<const bf16x8*>(&Kb[l5 * 64 + ch]);
            bf16x8 k1 = *reinterpret_cast<const bf16x8*>(&Kb[(32 + l5) * 64 + ch]);
            s0 = __builtin_amdgcn_mfma_f32_32x32x16_bf16(k0, qf[ks], s0, 0, 0, 0);
            s1 = __builtin_amdgcn_mfma_f32_32x32x16_bf16(k1, qf[ks], s1, 0, 0, 0);
        }
        __builtin_amdgcn_s_setprio(0);

        float p0[16], p1[16];
        float pmax = -1e30f;
        #pragma unroll
        for (int g = 0; g < 4; ++g) {
            float4 mb0 = *reinterpret_cast<const float4*>(&msk[kt + g * 8 + hi * 4]);
            float4 mb1 = *reinterpret_cast<const float4*>(&msk[kt + 32 + g * 8 + hi * 4]);
            #pragma unroll
            for (int i = 0; i < 4; ++i) {
                float mbv0 = (i == 0) ? mb0.x : (i == 1) ? mb0.y : (i == 2) ? mb0.z : mb0.w;
                float mbv1 = (i == 0) ? mb1.x : (i == 1) ? mb1.y : (i == 2) ? mb1.z : mb1.w;
                float a0 = fmaf(s0[g * 4 + i], 0.125f, mbv0);
                float a1 = fmaf(s1[g * 4 + i], 0.125f, mbv1);
                p0[g * 4 + i] = a0;
                p1[g * 4 + i] = a1;
                pmax = fmaxf(pmax, fmaxf(a0, a1));
            }
        }
        pmax = fmaxf(pmax, __shfl_xor(pmax, 32));
        float mnew = fmaxf(m_run, pmax);
        if (!__all(pmax - m_run <= 8.0f)) {          // defer-max (T13)
            float alpha = __expf(m_run - mnew);
            m_run = mnew;
            l_half *= alpha;
            als[w][l5] = alpha;
            #pragma unroll
            for (int g = 0; g < 4; ++g) {
                float4 av = *reinterpret_cast<const float4*>(&als[w][g * 8 + hi * 4]);
                o0[g * 4 + 0] *= av.x; o0[g * 4 + 1] *= av.y;
                o0[g * 4 + 2] *= av.z; o0[g * 4 + 3] *= av.w;
                o1[g * 4 + 0] *= av.x; o1[g * 4 + 1] *= av.y;
                o1[g * 4 + 2] *= av.z; o1[g * 4 + 3] *= av.w;
            }
        }
        float sum = 0.f;
        #pragma unroll
        for (int rg = 0; rg < 16; ++rg) {
            p0[rg] = __expf(p0[rg] - m_run);
            p1[rg] = __expf(p1[rg] - m_run);
            sum += p0[rg] + p1[rg];
        }
        l_half += sum;

        __builtin_amdgcn_s_setprio(1);
        #pragma unroll
        for (int tile = 0; tile < 2; ++tile) {
            const float* pp = tile ? p1 : p0;
            #pragma unroll
            for (int kp = 0; kp < 2; ++kp) {
                unsigned uA0 = cvtpk_bf16(pp[8 * kp + 0], pp[8 * kp + 1]);
                unsigned uA1 = cvtpk_bf16(pp[8 * kp + 2], pp[8 * kp + 3]);
                unsigned uB0 = cvtpk_bf16(pp[8 * kp + 4], pp[8 * kp + 5]);
                unsigned uB1 = cvtpk_bf16(pp[8 * kp + 6], pp[8 * kp + 7]);
                unsigned us0 = hi ? uB0 : uA0, us1 = hi ? uB1 : uA1;
                unsigned ug0 = hi ? uA0 : uB0, ug1 = hi ? uA1 : uB1;
                unsigned r0 = (unsigned)__shfl_xor((int)ug0, 32);
                unsigned r1 = (unsigned)__shfl_xor((int)ug1, 32);
                u32x4 pw_;
                pw_[0] = hi ? r0 : us0;
                pw_[1] = hi ? r1 : us1;
                pw_[2] = hi ? us0 : r0;
                pw_[3] = hi ? us1 : r1;
                bf16x8 pf = *reinterpret_cast<bf16x8*>(&pw_);
                int vch = (((tile << 2) + (kp << 1) + hi) ^ (l5 & 7)) << 3;
                bf16x8 v0 = *reinterpret_cast<const bf16x8*>(&Vb[l5 * 64 + vch]);
                bf16x8 v1 = *reinterpret_cast<const bf16x8*>(&Vb[(32 + l5) * 64 + vch]);
                o0 = __builtin_amdgcn_mfma_f32_32x32x16_bf16(pf, v0, o0, 0, 0, 0);
                o1 = __builtin_amdgcn_mfma_f32_32x32x16_bf16(pf, v1, o1, 0, 0, 0);
            }
        }
        __builtin_amdgcn_s_setprio(0);
    }

    float l_tot = l_half + __shfl_xor(l_half, 32);
    als[w][l5] = 1.0f / l_tot;
    bf16* ob = out + (size_t)(b * 1024 + qrow0) * DM + h * 64;
    #pragma unroll
    for (int g = 0; g < 4; ++g) {
        float4 iv = *reinterpret_cast<const float4*>(&als[w][g * 8 + hi * 4]);
        #pragma unroll
        for (int i = 0; i < 4; ++i) {
            float ivv = (i == 0) ? iv.x : (i == 1) ? iv.y : (i == 2) ? iv.z : iv.w;
            int qr = g * 8 + hi * 4 + i;
            ob[(size_t)qr * DM + l5]      = (bf16)(o0[g * 4 + i] * ivv);
            ob[(size_t)qr * DM + 32 + l5] = (bf16)(o1[g * 4 + i] * ivv);
        }
    }
}

// ---------------------------------------------------------------------------
extern "C" void kernel_launch(void* const* d_in, const int* in_sizes, int n_in,
                              void* d_out, int out_size, void* d_ws, size_t ws_size,
                              hipStream_t stream) {
    const float* x      = (const float*)d_in[0];
    const int*   mask   = (const int*)  d_in[1];
    const float* w_q    = (const float*)d_in[2];
    const float* w_k    = (const float*)d_in[3];
    const float* w_v    = (const float*)d_in[4];
    const float* w_o    = (const float*)d_in[5];
    const float* alpha1 = (const float*)d_in[6];
    const float* beta1  = (const float*)d_in[7];
    const float* alpha2 = (const float*)d_in[8];
    const float* beta2  = (const float*)d_in[9];
    const float* fc1_w  = (const float*)d_in[10];
    const float* fc1_b  = (const float*)d_in[11];
    const float* fc2_w  = (const float*)d_in[12];
    const float* fc2_b  = (const float*)d_in[13];
    float* out = (float*)d_out;

    char* ws = (char*)d_ws;
    const size_t MB = 1024 * 1024;
    bf16*  wqkv_b = (bf16*)(ws +  0 * MB);   // 6 MB
    bf16*  wo_b   = (bf16*)(ws +  6 * MB);   // 2 MB
    bf16*  f1w_b  = (bf16*)(ws +  8 * MB);   // 8 MB
    bf16*  f2w_b  = (bf16*)(ws + 16 * MB);   // 8 MB
    bf16*  xn     = (bf16*)(ws + 24 * MB);   // 4 MB
    bf16*  qkvb   = (bf16*)(ws + 28 * MB);   // 12 MB (Q,K; dead after attn)
    bf16*  vtb    = (bf16*)(ws + 40 * MB);   // 4 MB  (dead after attn)
    bf16*  attnb  = (bf16*)(ws + 44 * MB);   // 4 MB  (dead after o-proj)
    float* x2     = (float*)(ws + 48 * MB);  // 8 MB
    float* po     = (float*)(ws + 56 * MB);  // 32 MB o-proj partials (4 slices)
    bf16*  hb     = (bf16*)(ws + 28 * MB);   // 16 MB fc1 out (over qkvb/vtb)
    float* pf2    = (float*)(ws + 56 * MB);  // 32 MB fc2 partials (over po)

    // 1) wqkv -> bf16 + ln1
    prep_kernel<<<5120, 256, 0, stream>>>(
        (const float4*)w_q, (const float4*)w_k, (const float4*)w_v,
        (bf16x4*)wqkv_b, x, alpha1, beta1, xn);

    // 2) fused QKV projection (grid 24x16); V-range blocks write vtb
    gemm128<2><<<dim3(24, 16, 1), 256, 0, stream>>>(
        xn, wqkv_b, qkvb, vtb, nullptr, NTOK, QKVN, DM, DM, 24, 16);

    // 3) flash attention (256 blocks) + wo/fc1/fc2 conversion (2304 trailing)
    attn_kernel<<<2560, 256, 0, stream>>>(
        qkvb, vtb, mask, attnb,
        (const float4*)w_o, (const float4*)fc1_w, (const float4*)fc2_w,
        (bf16x4*)wo_b, (bf16x4*)f1w_b, (bf16x4*)f2w_b);

    // 4) o-proj split-K=4 partials (grid 8x16x4 -> 512 blocks, 2/CU)
    gemm128<4><<<dim3(8, 16, 4), 256, 0, stream>>>(
        attnb, wo_b, po, nullptr, nullptr, NTOK, DM, DM, DM / 4, 8, 16);

    // 5) reduce + residual -> x2, fused ln2 -> xn
    reduce_ln_kernel<<<NTOK, 256, 0, stream>>>(po, x, alpha2, beta2, x2, xn);

    // 6) fc1 + bias + relu (grid 32x16)
    gemm128<1><<<dim3(32, 16, 1), 256, 0, stream>>>(
        xn, f1w_b, hb, nullptr, fc1_b, NTOK, DFC, DM, DM, 32, 16);

    // 7) fc2 split-K=4 partials (grid 8x16x4 -> 512 blocks, 2/CU)
    gemm128<4><<<dim3(8, 16, 4), 256, 0, stream>>>(
        hb, f2w_b, pf2, nullptr, nullptr, NTOK, DM, DFC, DFC / 4, 8, 16);

    // 8) bias + residual -> out
    reduce_out_kernel<<<2048, 256, 0, stream>>>(pf2, fc2_b, x2, out);
}

// Round 10
// 235.760 us; speedup vs baseline: 1.2545x; 1.0149x over previous
//
#include <hip/hip_runtime.h>
#include <hip/hip_bf16.h>

// ---------------------------------------------------------------------------
// EncoderBlock round 19:
//  - r18 win kept (239.3us): swapped-QK 32x32 attn + conv-overlap trailing
//    blocks in attn dispatch.
//  - NEW gemm_3buf for fc1/fc2: 128x256 tile (r16's refcheck-verified
//    addressing), BK=64, 512 thr, LDS 3 x 48KB = 144KB (1 block/CU).
//    Pipeline: stage(t+2) issued during tile t (3 gl_lds calls per phase);
//    ONE raw s_barrier + counted s_waitcnt vmcnt(6) per K-tile (loads span
//    barriers; vmcnt(0) only at tail) = m218's counted-vs-drain mechanism
//    with a 3-deep buffer ring making the issue schedule provably race-free:
//      - stage(t+2) writes buf (t+2)%3, disjoint from buf t%3 (being read)
//        and buf (t+1)%3 (resident next); its previous reader (tile t-1)
//        passed the boundary barrier before tile t issues.
//      - boundary wait: outstanding = stage(t+1) 6 + stage(t+2) 6; vmcnt(6)
//        retires t+1 (FIFO) -> resident; leaves t+2 in flight.
//  - fc1: grid 16x16 full-K. fc2: grid 4x16 x split-K=4.
//  - QKV/o-proj: r12 gemm128. attn/prep/reduces: r18.
// MFMA layouts (verified): 16x16: A[m=lane&15][k=(lane>>4)*8+j],
//   B[k][n=lane&15], C row=(lane>>4)*4+reg, col=lane&15.
//   32x32 C: col=lane&31, row=(reg&3)+8*(reg>>2)+4*(lane>>5). (r17 refcheck)
// ---------------------------------------------------------------------------

typedef __bf16 bf16;
typedef __attribute__((ext_vector_type(8))) __bf16 bf16x8;
typedef __attribute__((ext_vector_type(4))) __bf16 bf16x4;
typedef __attribute__((ext_vector_type(4))) float f32x4;
typedef __attribute__((ext_vector_type(16))) float f32x16;
typedef __attribute__((ext_vector_type(4))) unsigned int u32x4;

#define NTOK 2048
#define DM   1024
#define DFC  4096
#define QKVN 3072

__device__ inline void gl_lds16(const void* g, void* l) {
    __builtin_amdgcn_global_load_lds((const __attribute__((address_space(1))) void*)g,
                                     (__attribute__((address_space(3))) void*)l, 16, 0, 0);
}

__device__ inline unsigned cvtpk_bf16(float lo, float hi) {
    unsigned r;
    asm("v_cvt_pk_bf16_f32 %0, %1, %2" : "=v"(r) : "v"(lo), "v"(hi));
    return r;
}

// ---------------- LayerNorm row helper (torch: std ddof=1, /(std+eps)) -----
__device__ inline void ln_row(float4 v, const float* alpha, const float* beta,
                              bf16* outrow, int t) {
    float s  = v.x + v.y + v.z + v.w;
    float ss = v.x * v.x + v.y * v.y + v.z * v.z + v.w * v.w;
    __shared__ float red[8];
    int lane = t & 63, wv = t >> 6;
    #pragma unroll
    for (int o = 32; o > 0; o >>= 1) {
        s  += __shfl_down(s, o);
        ss += __shfl_down(ss, o);
    }
    if (lane == 0) { red[wv] = s; red[4 + wv] = ss; }
    __syncthreads();
    float S  = red[0] + red[1] + red[2] + red[3];
    float SS = red[4] + red[5] + red[6] + red[7];
    float mean = S * (1.0f / 1024.0f);
    float var  = (SS - S * mean) * (1.0f / 1023.0f);
    var = var < 0.f ? 0.f : var;
    float inv = 1.0f / (sqrtf(var) + 1e-6f);
    float4 a4 = reinterpret_cast<const float4*>(alpha)[t];
    float4 b4 = reinterpret_cast<const float4*>(beta)[t];
    bf16x4 o4;
    o4[0] = (bf16)(a4.x * (v.x - mean) * inv + b4.x);
    o4[1] = (bf16)(a4.y * (v.y - mean) * inv + b4.y);
    o4[2] = (bf16)(a4.z * (v.z - mean) * inv + b4.z);
    o4[3] = (bf16)(a4.w * (v.w - mean) * inv + b4.w);
    reinterpret_cast<bf16x4*>(outrow)[t] = o4;
}

// ---------------- prep: wqkv fp32->bf16 AND ln1 -----------------------------
__global__ __launch_bounds__(256) void prep_kernel(
    const float4* __restrict__ wq, const float4* __restrict__ wk,
    const float4* __restrict__ wv, bf16x4* __restrict__ oqkv,
    const float* __restrict__ x, const float* __restrict__ alpha1,
    const float* __restrict__ beta1, bf16* __restrict__ xn) {
    int blk = blockIdx.x;
    int t = threadIdx.x;
    if (blk < 3072) {
        int i = blk * 256 + t;
        const int Q = 262144;                        // 1024*1024/4
        float4 v = (i < Q) ? wq[i] : (i < 2 * Q) ? wk[i - Q] : wv[i - 2 * Q];
        bf16x4 o;
        o[0] = (bf16)v.x; o[1] = (bf16)v.y; o[2] = (bf16)v.z; o[3] = (bf16)v.w;
        oqkv[i] = o;
    } else {
        int row = blk - 3072;
        float4 v = reinterpret_cast<const float4*>(x + (size_t)row * DM)[t];
        ln_row(v, alpha1, beta1, xn + (size_t)row * DM, t);
    }
}

// ---- o-proj split-K=4 reduce + residual -> x2, fused ln2 -> xn (block=row) -
__global__ __launch_bounds__(256) void reduce_ln_kernel(const float* __restrict__ p,
                                                        const float* __restrict__ resid,
                                                        const float* __restrict__ alpha,
                                                        const float* __restrict__ beta,
                                                        float* __restrict__ x2,
                                                        bf16* __restrict__ xn) {
    int row = blockIdx.x, t = threadIdx.x;
    size_t i4 = (size_t)row * 256 + t;
    const size_t SL = 524288;   // M*N/4 float4 per slice
    float4 a = reinterpret_cast<const float4*>(p)[i4];
    float4 b = reinterpret_cast<const float4*>(p)[i4 + SL];
    float4 c = reinterpret_cast<const float4*>(p)[i4 + 2 * SL];
    float4 d = reinterpret_cast<const float4*>(p)[i4 + 3 * SL];
    float4 r = reinterpret_cast<const float4*>(resid)[i4];
    float4 v;
    v.x = a.x + b.x + c.x + d.x + r.x;
    v.y = a.y + b.y + c.y + d.y + r.y;
    v.z = a.z + b.z + c.z + d.z + r.z;
    v.w = a.w + b.w + c.w + d.w + r.w;
    reinterpret_cast<float4*>(x2)[i4] = v;
    ln_row(v, alpha, beta, xn + (size_t)row * DM, t);
}

// ---- fc2 split-K=4 reduce + bias + residual -> d_out (fp32) ----------------
__global__ __launch_bounds__(256) void reduce_out_kernel(const float* __restrict__ p,
                                                         const float* __restrict__ bias,
                                                         const float* __restrict__ x2,
                                                         float* __restrict__ out) {
    size_t i4 = (size_t)blockIdx.x * 256 + threadIdx.x;
    const size_t SL = 524288;
    float4 a = reinterpret_cast<const float4*>(p)[i4];
    float4 b = reinterpret_cast<const float4*>(p)[i4 + SL];
    float4 c = reinterpret_cast<const float4*>(p)[i4 + 2 * SL];
    float4 d = reinterpret_cast<const float4*>(p)[i4 + 3 * SL];
    float4 r = reinterpret_cast<const float4*>(x2)[i4];
    float4 bi = reinterpret_cast<const float4*>(bias)[i4 & 255];
    float4 o;
    o.x = a.x + b.x + c.x + d.x + r.x + bi.x;
    o.y = a.y + b.y + c.y + d.y + r.y + bi.y;
    o.z = a.z + b.z + c.z + d.z + r.z + bi.z;
    o.w = a.w + b.w + c.w + d.w + r.w + bi.w;
    reinterpret_cast<float4*>(out)[i4] = o;
}

// ---------------- GEMM: 128x128 tile, BK=64, dbuf, swizzled LDS (r12) -------
// EPI: 2 = QKV (V range n0>=2048 -> transposed vt); 4 = fp32 partial (split-K).
template <int EPI>
__global__ __launch_bounds__(256) void gemm128(const bf16* __restrict__ A,
                                               const bf16* __restrict__ Bt,
                                               void* __restrict__ outp,
                                               bf16* __restrict__ vt,
                                               int M, int N, int K, int kslice,
                                               int nbx, int nby) {
    __shared__ bf16 As[2][128 * 64];   // 32 KB
    __shared__ bf16 Bs[2][128 * 64];   // 32 KB
    int tid = threadIdx.x;
    int lane = tid & 63, wave = tid >> 6;
    int q = lane >> 4, r = lane & 15;
    int wm = wave >> 1, wn = wave & 1;

    int lid = blockIdx.y * nbx + blockIdx.x;
    int nxp = nbx >> 3;
    int xcd = lid & 7;
    int loc = lid >> 3;
    int bx = xcd * nxp + (loc % nxp);
    int by = loc / nxp;

    int m0 = by * 128, n0 = bx * 128;
    int kbeg = blockIdx.z * kslice;
    int nit = kslice / 64;
    f32x4 acc[4][4] = {};

    int srow = tid >> 3;
    int csrc = (tid & 7) ^ (srow & 7);
    const bf16* agp = A  + (size_t)(m0 + srow) * K + kbeg + csrc * 8;
    const bf16* bgp = Bt + (size_t)(n0 + srow) * K + kbeg + csrc * 8;

    int co0 = ((q ^ (r & 7)) * 8);
    int co1 = co0 ^ 32;
    int aoff = (wm * 64 + r) * 64;
    int boff = (wn * 64 + r) * 64;

    auto stage = [&](int it, int b) {
        int k0 = it * 64;
        #pragma unroll
        for (int j = 0; j < 4; ++j) {
            gl_lds16(agp + (size_t)j * 32 * K + k0, &As[b][tid * 8 + j * 2048]);
            gl_lds16(bgp + (size_t)j * 32 * K + k0, &Bs[b][tid * 8 + j * 2048]);
        }
    };

    stage(0, 0);
    for (int it = 0; it < nit; ++it) {
        __syncthreads();                       // drains stage(it)
        if (it + 1 < nit) stage(it + 1, (it + 1) & 1);
        const bf16* Ab = &As[it & 1][aoff];
        const bf16* Bb = &Bs[it & 1][boff];
        #pragma unroll
        for (int half = 0; half < 2; ++half) {
            int co = half ? co1 : co0;
            bf16x8 af[4], bfv[4];
            #pragma unroll
            for (int t = 0; t < 4; ++t)
                af[t] = *reinterpret_cast<const bf16x8*>(Ab + t * 1024 + co);
            #pragma unroll
            for (int u = 0; u < 4; ++u)
                bfv[u] = *reinterpret_cast<const bf16x8*>(Bb + u * 1024 + co);
            #pragma unroll
            for (int t = 0; t < 4; ++t)
                #pragma unroll
                for (int u = 0; u < 4; ++u)
                    acc[t][u] = __builtin_amdgcn_mfma_f32_16x16x32_bf16(af[t], bfv[u], acc[t][u], 0, 0, 0);
        }
    }

    if (EPI == 2 && n0 >= 2048) {
        int bb = m0 >> 10;
        int sb = (m0 & 1023) + wm * 64 + q * 4;
        int vrow0 = bb * 1024 + (n0 - 2048) + wn * 64;
        #pragma unroll
        for (int t = 0; t < 4; ++t) {
            #pragma unroll
            for (int u = 0; u < 4; ++u) {
                bf16x4 pk;
                #pragma unroll
                for (int i = 0; i < 4; ++i) pk[i] = (bf16)acc[t][u][i];
                *reinterpret_cast<bf16x4*>(vt + (size_t)(vrow0 + u * 16 + r) * 1024 + sb + t * 16) = pk;
            }
        }
        return;
    }

    size_t zoff = (size_t)blockIdx.z * M * N;
    #pragma unroll
    for (int t = 0; t < 4; ++t) {
        #pragma unroll
        for (int u = 0; u < 4; ++u) {
            #pragma unroll
            for (int i = 0; i < 4; ++i) {
                int mm = m0 + wm * 64 + t * 16 + q * 4 + i;
                int nn = n0 + wn * 64 + u * 16 + r;
                size_t idx = (size_t)mm * N + nn;
                float v = acc[t][u][i];
                if (EPI == 2) {
                    ((bf16*)outp)[idx] = (bf16)v;
                } else {
                    ((float*)outp)[zoff + idx] = v;
                }
            }
        }
    }
}

// ---------------- GEMM: 128x256 tile, BK=64, 3-BUFFER counted-vmcnt ---------
// 512 thr = 8 waves (2M x 4N), per-wave 64x64 = acc[4][4] (r16-verified
// addressing). LDS: As[3] 48KB + Bs[3] 96KB = 144KB -> 1 block/CU.
// Per K-tile: 2 phases (kk=0/1) x 16 MFMA; stage(t+2) split 3+3 calls across
// the phases; boundary = vmcnt(6) + raw s_barrier (vmcnt(0) at tail only).
// EPI: 1 = relu(v+bias) bf16; 4 = fp32 partial at z*M*N.
template <int EPI>
__global__ __launch_bounds__(512) void gemm_3buf(const bf16* __restrict__ A,
                                                 const bf16* __restrict__ Bt,
                                                 void* __restrict__ outp,
                                                 const float* __restrict__ bias,
                                                 int M, int N, int K, int kslice,
                                                 int nbx, int nby) {
    __shared__ bf16 As[3][128 * 64];   // 48 KB
    __shared__ bf16 Bs[3][256 * 64];   // 96 KB
    int tid = threadIdx.x;
    int lane = tid & 63, wave = tid >> 6;
    int q = lane >> 4, r = lane & 15;
    int wm = wave >> 2, wn = wave & 3;

    int bx, by;
    if (nbx >= 8) {                    // XCD-aware remap (nbx multiple of 8)
        int lid = blockIdx.y * nbx + blockIdx.x;
        int nxp = nbx >> 3;
        int xcd = lid & 7;
        int loc = lid >> 3;
        bx = xcd * nxp + (loc % nxp);
        by = loc / nxp;
    } else {
        bx = blockIdx.x; by = blockIdx.y;
    }

    int m0 = by * 128, n0 = bx * 256;
    int kbeg = blockIdx.z * kslice;
    int nt = kslice / 64;
    f32x4 acc[4][4] = {};

    int srow = tid >> 3;               // 0..63
    int csrc = (tid & 7) ^ (srow & 7);
    const bf16* agp = A  + (size_t)(m0 + srow) * K + kbeg + csrc * 8;
    const bf16* bgp = Bt + (size_t)(n0 + srow) * K + kbeg + csrc * 8;

    int co0 = ((q ^ (r & 7)) * 8);
    int aoff = (wm * 64 + r) * 64;
    int boff = (wn * 64 + r) * 64;

    // stage = 6 gl_lds calls: part0 = A rows 0-127 (2) + B rows 0-63 (1);
    // part1 = B rows 64-255 (3).
    auto stage_p0 = [&](int it, int b) {
        int k0 = it * 64;
        gl_lds16(agp + k0,                  &As[b][tid * 8]);
        gl_lds16(agp + (size_t)64 * K + k0, &As[b][4096 + tid * 8]);
        gl_lds16(bgp + k0,                  &Bs[b][tid * 8]);
    };
    auto stage_p1 = [&](int it, int b) {
        int k0 = it * 64;
        gl_lds16(bgp + (size_t)64 * K + k0,  &Bs[b][4096 + tid * 8]);
        gl_lds16(bgp + (size_t)128 * K + k0, &Bs[b][8192 + tid * 8]);
        gl_lds16(bgp + (size_t)192 * K + k0, &Bs[b][12288 + tid * 8]);
    };

    // prologue: tiles 0,1 staged; wait tile0 (vmcnt(6) leaves tile1 in flight)
    stage_p0(0, 0); stage_p1(0, 0);
    stage_p0(1, 1); stage_p1(1, 1);
    asm volatile("s_waitcnt vmcnt(6)" ::: "memory");
    __builtin_amdgcn_s_barrier();

    for (int t = 0; t < nt; ++t) {
        const bf16* Ab = &As[t % 3][aoff];
        const bf16* Bb = &Bs[t % 3][boff];
        bool pf = (t + 2) < nt;
        int nb = (t + 2) % 3;
        #pragma unroll
        for (int ph = 0; ph < 2; ++ph) {
            int co = co0 ^ (ph * 32);
            bf16x8 af[4], bfv[4];
            #pragma unroll
            for (int tt = 0; tt < 4; ++tt)
                af[tt] = *reinterpret_cast<const bf16x8*>(Ab + tt * 1024 + co);
            #pragma unroll
            for (int u = 0; u < 4; ++u)
                bfv[u] = *reinterpret_cast<const bf16x8*>(Bb + u * 1024 + co);
            if (pf) {
                if (ph == 0) stage_p0(t + 2, nb);
                else         stage_p1(t + 2, nb);
            }
            __builtin_amdgcn_s_setprio(1);
            #pragma unroll
            for (int tt = 0; tt < 4; ++tt)
                #pragma unroll
                for (int u = 0; u < 4; ++u)
                    acc[tt][u] = __builtin_amdgcn_mfma_f32_16x16x32_bf16(
                        af[tt], bfv[u], acc[tt][u], 0, 0, 0);
            __builtin_amdgcn_s_setprio(0);
        }
        if (t + 1 < nt) {
            if (pf) asm volatile("s_waitcnt vmcnt(6)" ::: "memory");
            else    asm volatile("s_waitcnt vmcnt(0)" ::: "memory");
            __builtin_amdgcn_s_barrier();
        }
    }

    size_t zoff = (size_t)blockIdx.z * M * N;
    #pragma unroll
    for (int tt = 0; tt < 4; ++tt) {
        #pragma unroll
        for (int u = 0; u < 4; ++u) {
            #pragma unroll
            for (int i = 0; i < 4; ++i) {
                int mm = m0 + wm * 64 + tt * 16 + q * 4 + i;
                int nn = n0 + wn * 64 + u * 16 + r;
                size_t idx = (size_t)mm * N + nn;
                float v = acc[tt][u][i];
                if (EPI == 1) {
                    v += bias[nn];
                    ((bf16*)outp)[idx] = (bf16)(v > 0.f ? v : 0.f);
                } else {
                    ((float*)outp)[zoff + idx] = v;
                }
            }
        }
    }
}

// ---------------- flash attention: swapped-QK 32x32, in-register softmax ----
// Blocks [0,256): attn (r17). Blocks [256,2560): wo/fc1/fc2 conversion.
__global__ __launch_bounds__(256) void attn_kernel(const bf16* __restrict__ qkv,
                                                   const bf16* __restrict__ Vt,
                                                   const int* __restrict__ mask,
                                                   bf16* __restrict__ out,
                                                   const float4* __restrict__ cwo,
                                                   const float4* __restrict__ cf1,
                                                   const float4* __restrict__ cf2,
                                                   bf16x4* __restrict__ oo,
                                                   bf16x4* __restrict__ of1,
                                                   bf16x4* __restrict__ of2) {
    __shared__ bf16 Ks[2][4096];     // 16 KB
    __shared__ bf16 Vs[2][4096];     // 16 KB
    __shared__ float msk[1024];      // 4 KB
    __shared__ float als[4][32];     // 512 B
    int tid = threadIdx.x;

    if (blockIdx.x >= 256) {         // ---- weight-conversion trailing blocks
        int base = (blockIdx.x - 256) * 1024;       // float4 units
        const int Q = 262144;                       // 1024*1024/4 float4
        #pragma unroll
        for (int k = 0; k < 4; ++k) {
            int i = base + k * 256 + tid;
            float4 v;
            bf16x4* dst;
            if (i < Q)          { v = cwo[i];         dst = oo  + i; }
            else if (i < 5 * Q) { v = cf1[i - Q];     dst = of1 + (i - Q); }
            else                { v = cf2[i - 5 * Q]; dst = of2 + (i - 5 * Q); }
            bf16x4 o;
            o[0] = (bf16)v.x; o[1] = (bf16)v.y; o[2] = (bf16)v.z; o[3] = (bf16)v.w;
            *dst = o;
        }
        return;
    }

    int lane = tid & 63, w = tid >> 6;
    int l5 = lane & 31, hi = lane >> 5;

    int id = blockIdx.x;
    int xcd = id & 7, jj = id >> 3;      // jj in [0,32)
    int bh = xcd * 4 + (jj >> 3);        // [0,32)
    int qb = jj & 7;                     // 8 q-tiles of 128 rows
    int b = bh >> 4, h = bh & 15;

    {
        int4 mi = reinterpret_cast<const int4*>(mask + b * 1024)[tid];
        msk[tid * 4 + 0] = mi.x ? 0.f : -1e9f;
        msk[tid * 4 + 1] = mi.y ? 0.f : -1e9f;
        msk[tid * 4 + 2] = mi.z ? 0.f : -1e9f;
        msk[tid * 4 + 3] = mi.w ? 0.f : -1e9f;
    }

    int qrow0 = qb * 128 + w * 32;
    const bf16* qp = qkv + (size_t)(b * 1024 + qrow0 + l5) * QKVN + h * 64 + hi * 8;
    bf16x8 qf[4];
    #pragma unroll
    for (int ks = 0; ks < 4; ++ks)
        qf[ks] = *reinterpret_cast<const bf16x8*>(qp + ks * 16);

    int csw = (tid & 7) ^ ((tid >> 3) & 7);
    const bf16* kg0 = qkv + (size_t)(b * 1024 + (tid >> 3)) * QKVN + 1024 + h * 64 + csw * 8;
    const bf16* kg1 = kg0 + (size_t)32 * QKVN;
    const bf16* vg0 = Vt + (size_t)((b * 16 + h) * 64 + (tid >> 3)) * 1024 + csw * 8;
    const bf16* vg1 = vg0 + 32 * 1024;
    bf16* kld = &Ks[0][tid * 8];
    bf16* vld = &Vs[0][tid * 8];

    gl_lds16(kg0, kld);
    gl_lds16(kg1, kld + 2048);
    gl_lds16(vg0, vld);
    gl_lds16(vg1, vld + 2048);

    float m_run = -1e30f, l_half = 0.f;
    f32x16 o0 = {};      // d = l5
    f32x16 o1 = {};      // d = 32 + l5

    for (int t = 0; t < 16; ++t) {
        __syncthreads();
        if (t < 15) {
            int ktn = (t + 1) * 64;
            int bo = ((t + 1) & 1) * 4096;
            gl_lds16(kg0 + (size_t)ktn * QKVN, kld + bo);
            gl_lds16(kg1 + (size_t)ktn * QKVN, kld + bo + 2048);
            gl_lds16(vg0 + ktn, vld + bo);
            gl_lds16(vg1 + ktn, vld + bo + 2048);
        }
        const bf16* Kb = Ks[t & 1];
        const bf16* Vb = Vs[t & 1];
        int kt = t * 64;

        f32x16 s0 = {}, s1 = {};
        __builtin_amdgcn_s_setprio(1);
        #pragma unroll
        for (int ks = 0; ks < 4; ++ks) {
            int ch = (((ks << 1) + hi) ^ (l5 & 7)) << 3;
            bf16x8 k0 = *reinterpret_cast<const bf16x8*>(&Kb[l5 * 64 + ch]);
            bf16x8 k1 = *reinterpret_cast<const bf16x8*>(&Kb[(32 + l5) * 64 + ch]);
            s0 = __builtin_amdgcn_mfma_f32_32x32x16_bf16(k0, qf[ks], s0, 0, 0, 0);
            s1 = __builtin_amdgcn_mfma_f32_32x32x16_bf16(k1, qf[ks], s1, 0, 0, 0);
        }
        __builtin_amdgcn_s_setprio(0);

        float p0[16], p1[16];
        float pmax = -1e30f;
        #pragma unroll
        for (int g = 0; g < 4; ++g) {
            float4 mb0 = *reinterpret_cast<const float4*>(&msk[kt + g * 8 + hi * 4]);
            float4 mb1 = *reinterpret_cast<const float4*>(&msk[kt + 32 + g * 8 + hi * 4]);
            #pragma unroll
            for (int i = 0; i < 4; ++i) {
                float mbv0 = (i == 0) ? mb0.x : (i == 1) ? mb0.y : (i == 2) ? mb0.z : mb0.w;
                float mbv1 = (i == 0) ? mb1.x : (i == 1) ? mb1.y : (i == 2) ? mb1.z : mb1.w;
                float a0 = fmaf(s0[g * 4 + i], 0.125f, mbv0);
                float a1 = fmaf(s1[g * 4 + i], 0.125f, mbv1);
                p0[g * 4 + i] = a0;
                p1[g * 4 + i] = a1;
                pmax = fmaxf(pmax, fmaxf(a0, a1));
            }
        }
        pmax = fmaxf(pmax, __shfl_xor(pmax, 32));
        float mnew = fmaxf(m_run, pmax);
        if (!__all(pmax - m_run <= 8.0f)) {          // defer-max (T13)
            float alpha = __expf(m_run - mnew);
            m_run = mnew;
            l_half *= alpha;
            als[w][l5] = alpha;
            #pragma unroll
            for (int g = 0; g < 4; ++g) {
                float4 av = *reinterpret_cast<const float4*>(&als[w][g * 8 + hi * 4]);
                o0[g * 4 + 0] *= av.x; o0[g * 4 + 1] *= av.y;
                o0[g * 4 + 2] *= av.z; o0[g * 4 + 3] *= av.w;
                o1[g * 4 + 0] *= av.x; o1[g * 4 + 1] *= av.y;
                o1[g * 4 + 2] *= av.z; o1[g * 4 + 3] *= av.w;
            }
        }
        float sum = 0.f;
        #pragma unroll
        for (int rg = 0; rg < 16; ++rg) {
            p0[rg] = __expf(p0[rg] - m_run);
            p1[rg] = __expf(p1[rg] - m_run);
            sum += p0[rg] + p1[rg];
        }
        l_half += sum;

        __builtin_amdgcn_s_setprio(1);
        #pragma unroll
        for (int tile = 0; tile < 2; ++tile) {
            const float* pp = tile ? p1 : p0;
            #pragma unroll
            for (int kp = 0; kp < 2; ++kp) {
                unsigned uA0 = cvtpk_bf16(pp[8 * kp + 0], pp[8 * kp + 1]);
                unsigned uA1 = cvtpk_bf16(pp[8 * kp + 2], pp[8 * kp + 3]);
                unsigned uB0 = cvtpk_bf16(pp[8 * kp + 4], pp[8 * kp + 5]);
                unsigned uB1 = cvtpk_bf16(pp[8 * kp + 6], pp[8 * kp + 7]);
                unsigned us0 = hi ? uB0 : uA0, us1 = hi ? uB1 : uA1;
                unsigned ug0 = hi ? uA0 : uB0, ug1 = hi ? uA1 : uB1;
                unsigned r0 = (unsigned)__shfl_xor((int)ug0, 32);
                unsigned r1 = (unsigned)__shfl_xor((int)ug1, 32);
                u32x4 pw_;
                pw_[0] = hi ? r0 : us0;
                pw_[1] = hi ? r1 : us1;
                pw_[2] = hi ? us0 : r0;
                pw_[3] = hi ? us1 : r1;
                bf16x8 pf = *reinterpret_cast<bf16x8*>(&pw_);
                int vch = (((tile << 2) + (kp << 1) + hi) ^ (l5 & 7)) << 3;
                bf16x8 v0 = *reinterpret_cast<const bf16x8*>(&Vb[l5 * 64 + vch]);
                bf16x8 v1 = *reinterpret_cast<const bf16x8*>(&Vb[(32 + l5) * 64 + vch]);
                o0 = __builtin_amdgcn_mfma_f32_32x32x16_bf16(pf, v0, o0, 0, 0, 0);
                o1 = __builtin_amdgcn_mfma_f32_32x32x16_bf16(pf, v1, o1, 0, 0, 0);
            }
        }
        __builtin_amdgcn_s_setprio(0);
    }

    float l_tot = l_half + __shfl_xor(l_half, 32);
    als[w][l5] = 1.0f / l_tot;
    bf16* ob = out + (size_t)(b * 1024 + qrow0) * DM + h * 64;
    #pragma unroll
    for (int g = 0; g < 4; ++g) {
        float4 iv = *reinterpret_cast<const float4*>(&als[w][g * 8 + hi * 4]);
        #pragma unroll
        for (int i = 0; i < 4; ++i) {
            float ivv = (i == 0) ? iv.x : (i == 1) ? iv.y : (i == 2) ? iv.z : iv.w;
            int qr = g * 8 + hi * 4 + i;
            ob[(size_t)qr * DM + l5]      = (bf16)(o0[g * 4 + i] * ivv);
            ob[(size_t)qr * DM + 32 + l5] = (bf16)(o1[g * 4 + i] * ivv);
        }
    }
}

// ---------------------------------------------------------------------------
extern "C" void kernel_launch(void* const* d_in, const int* in_sizes, int n_in,
                              void* d_out, int out_size, void* d_ws, size_t ws_size,
                              hipStream_t stream) {
    const float* x      = (const float*)d_in[0];
    const int*   mask   = (const int*)  d_in[1];
    const float* w_q    = (const float*)d_in[2];
    const float* w_k    = (const float*)d_in[3];
    const float* w_v    = (const float*)d_in[4];
    const float* w_o    = (const float*)d_in[5];
    const float* alpha1 = (const float*)d_in[6];
    const float* beta1  = (const float*)d_in[7];
    const float* alpha2 = (const float*)d_in[8];
    const float* beta2  = (const float*)d_in[9];
    const float* fc1_w  = (const float*)d_in[10];
    const float* fc1_b  = (const float*)d_in[11];
    const float* fc2_w  = (const float*)d_in[12];
    const float* fc2_b  = (const float*)d_in[13];
    float* out = (float*)d_out;

    char* ws = (char*)d_ws;
    const size_t MB = 1024 * 1024;
    bf16*  wqkv_b = (bf16*)(ws +  0 * MB);   // 6 MB
    bf16*  wo_b   = (bf16*)(ws +  6 * MB);   // 2 MB
    bf16*  f1w_b  = (bf16*)(ws +  8 * MB);   // 8 MB
    bf16*  f2w_b  = (bf16*)(ws + 16 * MB);   // 8 MB
    bf16*  xn     = (bf16*)(ws + 24 * MB);   // 4 MB
    bf16*  qkvb   = (bf16*)(ws + 28 * MB);   // 12 MB (Q,K; dead after attn)
    bf16*  vtb    = (bf16*)(ws + 40 * MB);   // 4 MB  (dead after attn)
    bf16*  attnb  = (bf16*)(ws + 44 * MB);   // 4 MB  (dead after o-proj)
    float* x2     = (float*)(ws + 48 * MB);  // 8 MB
    float* po     = (float*)(ws + 56 * MB);  // 32 MB o-proj partials (4 slices)
    bf16*  hb     = (bf16*)(ws + 28 * MB);   // 16 MB fc1 out (over qkvb/vtb)
    float* pf2    = (float*)(ws + 56 * MB);  // 32 MB fc2 partials (over po)

    // 1) wqkv -> bf16 + ln1
    prep_kernel<<<5120, 256, 0, stream>>>(
        (const float4*)w_q, (const float4*)w_k, (const float4*)w_v,
        (bf16x4*)wqkv_b, x, alpha1, beta1, xn);

    // 2) fused QKV projection (grid 24x16); V-range blocks write vtb
    gemm128<2><<<dim3(24, 16, 1), 256, 0, stream>>>(
        xn, wqkv_b, qkvb, vtb, NTOK, QKVN, DM, DM, 24, 16);

    // 3) flash attention (256 blocks) + wo/fc1/fc2 conversion (2304 trailing)
    attn_kernel<<<2560, 256, 0, stream>>>(
        qkvb, vtb, mask, attnb,
        (const float4*)w_o, (const float4*)fc1_w, (const float4*)fc2_w,
        (bf16x4*)wo_b, (bf16x4*)f1w_b, (bf16x4*)f2w_b);

    // 4) o-proj split-K=4 partials (grid 8x16x4 -> 512 blocks, 2/CU)
    gemm128<4><<<dim3(8, 16, 4), 256, 0, stream>>>(
        attnb, wo_b, po, nullptr, NTOK, DM, DM, DM / 4, 8, 16);

    // 5) reduce + residual -> x2, fused ln2 -> xn
    reduce_ln_kernel<<<NTOK, 256, 0, stream>>>(po, x, alpha2, beta2, x2, xn);

    // 6) fc1 + bias + relu: 3-buf counted-vmcnt 128x256 (grid 16x16, 1/CU)
    gemm_3buf<1><<<dim3(16, 16, 1), 512, 0, stream>>>(
        xn, f1w_b, hb, fc1_b, NTOK, DFC, DM, DM, 16, 16);

    // 7) fc2: 3-buf counted-vmcnt 128x256, split-K=4 (grid 4x16x4 = 256)
    gemm_3buf<4><<<dim3(4, 16, 4), 512, 0, stream>>>(
        hb, f2w_b, pf2, nullptr, NTOK, DM, DFC, DFC / 4, 4, 16);

    // 8) bias + residual -> out
    reduce_out_kernel<<<2048, 256, 0, stream>>>(pf2, fc2_b, x2, out);
}